// Round 13
// baseline (3163.901 us; speedup 1.0000x reference)
//
#include <hip/hip_runtime.h>
#include <math.h>

#define B_ 16
#define S_ 256
#define H_ 768
#define L_ 12
#define NH_ 12
#define DH_ 64
#define FF_ 3072
#define T_ 9

typedef unsigned short ushort_t;
typedef __attribute__((ext_vector_type(8))) __bf16 bf16x8;
typedef __attribute__((ext_vector_type(4))) float f32x4;
typedef __attribute__((ext_vector_type(4))) unsigned short us4;
typedef __attribute__((ext_vector_type(4))) unsigned int u32x4;

__device__ __forceinline__ ushort_t f2bf(float f) {
  union { float f; unsigned u; } v; v.f = f;
  unsigned r = v.u + 0x7FFFu + ((v.u >> 16) & 1u);
  return (ushort_t)(r >> 16);
}
__device__ __forceinline__ float bf2f(ushort_t h) {
  union { unsigned u; float f; } v; v.u = ((unsigned)h) << 16;
  return v.f;
}
__device__ __forceinline__ void gload16(const void* g, void* l) {
  __builtin_amdgcn_global_load_lds((const __attribute__((address_space(1))) void*)g,
                                   (__attribute__((address_space(3))) void*)l, 16, 0, 0);
}

// ---------------- fused embedding sum + layernorm ----------------
__global__ __launch_bounds__(256) void emb_ln_kernel(const int* __restrict__ ids, const int* __restrict__ tt,
                              const float* __restrict__ we, const float* __restrict__ pe,
                              const float* __restrict__ te, const float* __restrict__ g,
                              const float* __restrict__ bb, float* __restrict__ out,
                              ushort_t* __restrict__ oh, ushort_t* __restrict__ ol) {
  const int token = blockIdx.x;
  const int tid = threadIdx.x;
  const int s = token & (S_ - 1);
  const int id = ids[token];
  const int t2 = tt[token];
  float x[3];
  float sum = 0.f;
#pragma unroll
  for (int i = 0; i < 3; ++i) {
    int d = tid + i * 256;
    x[i] = we[(size_t)id * H_ + d] + pe[(size_t)s * H_ + d] + te[(size_t)t2 * H_ + d];
    sum += x[i];
  }
  __shared__ float red[4];
#pragma unroll
  for (int o = 32; o > 0; o >>= 1) sum += __shfl_xor(sum, o, 64);
  const int wid = tid >> 6, lane = tid & 63;
  if (lane == 0) red[wid] = sum;
  __syncthreads();
  const float mean = (red[0] + red[1] + red[2] + red[3]) * (1.f / H_);
  float vs = 0.f;
#pragma unroll
  for (int i = 0; i < 3; ++i) { float dv = x[i] - mean; vs += dv * dv; }
#pragma unroll
  for (int o = 32; o > 0; o >>= 1) vs += __shfl_xor(vs, o, 64);
  __syncthreads();
  if (lane == 0) red[wid] = vs;
  __syncthreads();
  const float var = (red[0] + red[1] + red[2] + red[3]) * (1.f / H_);
  const float inv = rsqrtf(var + 1e-12f);
  float* op = out + (size_t)token * H_;
  ushort_t* hp = oh + (size_t)token * H_;
  ushort_t* lp = ol + (size_t)token * H_;
#pragma unroll
  for (int i = 0; i < 3; ++i) {
    int d = tid + i * 256;
    float y = (x[i] - mean) * inv * g[d] + bb[d];
    op[d] = y;
    ushort_t h = f2bf(y);
    hp[d] = h;
    lp[d] = f2bf(y - bf2f(h));
  }
}

// ---------------- layernorm (+residual), writes f32 + bf16 hi/lo ----------------
__global__ __launch_bounds__(256) void ln_kernel(const float* __restrict__ base, const float* __restrict__ delta,
                          const float* __restrict__ g, const float* __restrict__ bb,
                          float* __restrict__ out, ushort_t* __restrict__ oh, ushort_t* __restrict__ ol) {
  const int token = blockIdx.x;
  const int tid = threadIdx.x;
  const float* bp = base + (size_t)token * H_;
  const float* dp = delta + (size_t)token * H_;
  float x[3];
  float s = 0.f;
#pragma unroll
  for (int i = 0; i < 3; ++i) { int d = tid + i * 256; x[i] = bp[d] + dp[d]; s += x[i]; }
  __shared__ float red[4];
#pragma unroll
  for (int o = 32; o > 0; o >>= 1) s += __shfl_xor(s, o, 64);
  const int wid = tid >> 6, lane = tid & 63;
  if (lane == 0) red[wid] = s;
  __syncthreads();
  const float mean = (red[0] + red[1] + red[2] + red[3]) * (1.f / H_);
  float vs = 0.f;
#pragma unroll
  for (int i = 0; i < 3; ++i) { float dv = x[i] - mean; vs += dv * dv; }
#pragma unroll
  for (int o = 32; o > 0; o >>= 1) vs += __shfl_xor(vs, o, 64);
  __syncthreads();
  if (lane == 0) red[wid] = vs;
  __syncthreads();
  const float var = (red[0] + red[1] + red[2] + red[3]) * (1.f / H_);
  const float inv = rsqrtf(var + 1e-12f);
  float* op = out + (size_t)token * H_;
  ushort_t* hp = oh + (size_t)token * H_;
  ushort_t* lp = ol + (size_t)token * H_;
#pragma unroll
  for (int i = 0; i < 3; ++i) {
    int d = tid + i * 256;
    float y = (x[i] - mean) * inv * g[d] + bb[d];
    op[d] = y;
    ushort_t h = f2bf(y);
    hp[d] = h;
    lp[d] = f2bf(y - bf2f(h));
  }
}

// ---------------- final layernorm + emissions fused (no X/Xh/Xl writes) ----------------
__global__ __launch_bounds__(256) void ln_emis_kernel(const float* __restrict__ base, const float* __restrict__ delta,
                               const float* __restrict__ g, const float* __restrict__ bb,
                               const float* __restrict__ W, const float* __restrict__ wbias,
                               float* __restrict__ E) {
  const int token = blockIdx.x;
  const int tid = threadIdx.x;
  __shared__ float sW[H_ * T_];     // 27 KB
  __shared__ float red[4];
  __shared__ float wred[4][12];
  for (int i = tid; i < H_ * T_; i += 256) sW[i] = W[i];

  const float* bp = base + (size_t)token * H_;
  const float* dp = delta + (size_t)token * H_;
  float x[3];
  float s = 0.f;
#pragma unroll
  for (int i = 0; i < 3; ++i) { int d = tid + i * 256; x[i] = bp[d] + dp[d]; s += x[i]; }
#pragma unroll
  for (int o = 32; o > 0; o >>= 1) s += __shfl_xor(s, o, 64);
  const int wid = tid >> 6, lane = tid & 63;
  if (lane == 0) red[wid] = s;
  __syncthreads();
  const float mean = (red[0] + red[1] + red[2] + red[3]) * (1.f / H_);
  float vs = 0.f;
#pragma unroll
  for (int i = 0; i < 3; ++i) { float dv = x[i] - mean; vs += dv * dv; }
#pragma unroll
  for (int o = 32; o > 0; o >>= 1) vs += __shfl_xor(vs, o, 64);
  __syncthreads();
  if (lane == 0) red[wid] = vs;
  __syncthreads();
  const float var = (red[0] + red[1] + red[2] + red[3]) * (1.f / H_);
  const float inv = rsqrtf(var + 1e-12f);

  float acc9[T_];
#pragma unroll
  for (int t = 0; t < T_; ++t) acc9[t] = 0.f;
#pragma unroll
  for (int i = 0; i < 3; ++i) {
    int d = tid + i * 256;
    float y = (x[i] - mean) * inv * g[d] + bb[d];
    const float* wr = sW + d * T_;
#pragma unroll
    for (int t = 0; t < T_; ++t) acc9[t] = fmaf(y, wr[t], acc9[t]);
  }
#pragma unroll
  for (int o = 32; o > 0; o >>= 1)
#pragma unroll
    for (int t = 0; t < T_; ++t) acc9[t] += __shfl_xor(acc9[t], o, 64);
  if (lane == 0) {
#pragma unroll
    for (int t = 0; t < T_; ++t) wred[wid][t] = acc9[t];
  }
  __syncthreads();
  if (tid < T_) {
    const float v = wred[0][tid] + wred[1][tid] + wred[2][tid] + wred[3][tid] + wbias[tid];
    const int b2 = token >> 8, s2 = token & 255;
    E[((size_t)s2 * B_ + b2) * T_ + tid] = v;
  }
}

// ---------------- weight transpose + bf16 round: src[K][N] f32 -> dst[N][K] ----------------
__device__ __forceinline__ void transpose_core(float (*t)[65], const float* __restrict__ src,
                                               ushort_t* __restrict__ dh,
                                               int K, int N, int n0, int k0) {
  const int tid = threadIdx.x;
#pragma unroll
  for (int i = 0; i < 16; ++i) {
    int lin = tid + i * 256;
    int kk = lin >> 6, nn = lin & 63;
    t[kk][nn] = src[(size_t)(k0 + kk) * N + n0 + nn];
  }
  __syncthreads();
#pragma unroll
  for (int i = 0; i < 16; ++i) {
    int lin = tid + i * 256;
    int nn = lin >> 6, kk = lin & 63;
    dh[(size_t)(n0 + nn) * K + k0 + kk] = f2bf(t[kk][nn]);
  }
}

__device__ __forceinline__ void wprep_dispatch(float (*t)[65], int wid,
                        const float* Wq, const float* Wk, const float* Wv, const float* Wo,
                        const float* W1, const float* W2,
                        ushort_t* WT4h, ushort_t* W1th, ushort_t* W2th) {
  if (wid < 576) {
    const int z = wid / 144, r = wid - z * 144;
    const int x = r % 12, y = r / 12;
    const float* src = z == 0 ? Wq : (z == 1 ? Wk : (z == 2 ? Wv : Wo));
    transpose_core(t, src, WT4h + (size_t)z * H_ * H_, H_, H_, x * 64, y * 64);
  } else if (wid < 1152) {
    const int i = wid - 576;
    const int x = i % 48, y = i / 48;
    transpose_core(t, W1, W1th, H_, FF_, x * 64, y * 64);
  } else {
    const int i = wid - 1152;
    const int x = i % 12, y = i / 12;
    transpose_core(t, W2, W2th, FF_, H_, x * 64, y * 64);
  }
}

__global__ __launch_bounds__(256) void wprep_k(const float* __restrict__ Wq, const float* __restrict__ Wk,
                        const float* __restrict__ Wv, const float* __restrict__ Wo,
                        const float* __restrict__ W1, const float* __restrict__ W2,
                        ushort_t* __restrict__ WT4h,
                        ushort_t* __restrict__ W1th, ushort_t* __restrict__ W2th) {
  __shared__ float t[64][65];
  wprep_dispatch(t, blockIdx.x, Wq, Wk, Wv, Wo, W1, W2, WT4h, W1th, W2th);
}

// ---------------- conflict-free staging (proven mapping), one 32-K slice ----------------
template <int R>
__device__ __forceinline__ void stage_slice(const ushort_t* __restrict__ gsrc, int K, char* lds) {
  const int tid = threadIdx.x;
  constexpr int NIT = (R * 4) / 256;
#pragma unroll
  for (int i = 0; i < NIT; ++i) {
    const int v = tid + i * 256;
    const int kh = v / (2 * R);
    const int r2 = v & (2 * R - 1);
    const int row = r2 >> 1;
    const int kg = (kh << 1) | ((r2 & 1) ^ ((row >> 2) & 1));
    gload16(gsrc + (size_t)row * K + kg * 8, lds + (i * 256 + (tid & 192)) * 16);
  }
}

// ---------------- split-A MFMA GEMM core, double-buffered: acc = (Ah+Al) * Bh^T ----------------
template <int BM, int BN, int BK>
__device__ __forceinline__ void mgemm_acc(
    const ushort_t* __restrict__ Ah, const ushort_t* __restrict__ Al,
    const ushort_t* __restrict__ Bth,
    int K, f32x4 (&acc)[BM / 32][BN / 32], char* pool) {
  constexpr int FM = BM / 32;
  constexpr int FN = BN / 32;
  constexpr int ABYTES = BM * BK * 2;
  constexpr int BBYTES = BN * BK * 2;
  constexpr int BUF = 2 * ABYTES + BBYTES;
  constexpr int NL = (8 * BM + 4 * BN) / 256;   // per-thread loads per K-step (BK=32)
  const int tid = threadIdx.x;
  const int w = tid >> 6, lane = tid & 63;
  const int wm = w >> 1, wn = w & 1;
  const int kgL = lane >> 4, lr = lane & 15;
  const int row0 = blockIdx.y * BM, col0 = blockIdx.x * BN;

#pragma unroll
  for (int i = 0; i < FM; ++i)
#pragma unroll
    for (int j = 0; j < FN; ++j) acc[i][j] = (f32x4){0.f, 0.f, 0.f, 0.f};

  const int khL = kgL >> 1;
  const int swz = (((kgL & 1) ^ ((lr >> 2) & 1)) << 4);
  const int aB0 = khL * (BM * 32) + (wm * (BM / 2) + lr) * 32 + swz;
  const int bB0 = khL * (BN * 32) + (wn * (BN / 2) + lr) * 32 + swz;

  const ushort_t* gA_h = Ah + (size_t)row0 * K;
  const ushort_t* gA_l = Al + (size_t)row0 * K;
  const ushort_t* gB_h = Bth + (size_t)col0 * K;

  auto stageall = [&](int k0, char* buf) {
#pragma unroll
    for (int c = 0; c < BK / 32; ++c) {
      stage_slice<BM>(gA_h + k0 + c * 32, K, buf + c * BM * 64);
      stage_slice<BM>(gA_l + k0 + c * 32, K, buf + ABYTES + c * BM * 64);
      stage_slice<BN>(gB_h + k0 + c * 32, K, buf + 2 * ABYTES + c * BN * 64);
    }
  };

  const int nk = K / BK;
  stageall(0, pool);
  for (int k = 0; k < nk; ++k) {
    char* cur = pool + (k & 1) * BUF;
    if (k + 1 < nk) {
      stageall((k + 1) * BK, pool + ((k + 1) & 1) * BUF);
      if constexpr (NL == 6) {
        asm volatile("s_waitcnt vmcnt(6)" ::: "memory");
      } else if constexpr (NL == 8) {
        asm volatile("s_waitcnt vmcnt(8)" ::: "memory");
      } else {
        asm volatile("s_waitcnt vmcnt(0)" ::: "memory");
      }
    } else {
      asm volatile("s_waitcnt vmcnt(0)" ::: "memory");
    }
    __builtin_amdgcn_s_barrier();
    asm volatile("" ::: "memory");

#pragma unroll
    for (int ks = 0; ks < BK / 32; ++ks) {
      const char* aP = cur + ks * BM * 64;
      const char* bP = cur + 2 * ABYTES + ks * BN * 64;
      bf16x8 a_h[FM], a_l[FM], b_h[FN];
#pragma unroll
      for (int fm = 0; fm < FM; ++fm) {
        a_h[fm] = *(const bf16x8*)(aP + aB0 + fm * 512);
        a_l[fm] = *(const bf16x8*)(aP + ABYTES + aB0 + fm * 512);
      }
#pragma unroll
      for (int fn = 0; fn < FN; ++fn) {
        b_h[fn] = *(const bf16x8*)(bP + bB0 + fn * 512);
      }
#pragma unroll
      for (int fm = 0; fm < FM; ++fm)
#pragma unroll
        for (int fn = 0; fn < FN; ++fn) {
          f32x4 c = acc[fm][fn];
          c = __builtin_amdgcn_mfma_f32_16x16x32_bf16(a_h[fm], b_h[fn], c, 0, 0, 0);
          c = __builtin_amdgcn_mfma_f32_16x16x32_bf16(a_l[fm], b_h[fn], c, 0, 0, 0);
          acc[fm][fn] = c;
        }
    }
    asm volatile("" ::: "memory");
    __builtin_amdgcn_s_barrier();   // readers done before restage of this buf
  }
}

// generic GEMM, EPI 0: f32 out
template <int BM, int BN, int BK, int EPI>
__global__ __launch_bounds__(256, 3) void mgemm(const ushort_t* __restrict__ Ah, const ushort_t* __restrict__ Al,
                      const ushort_t* __restrict__ Bth,
                      const float* __restrict__ bias, float* __restrict__ Cf,
                      ushort_t* __restrict__ Ch, ushort_t* __restrict__ Cl, int N, int K) {
  __shared__ __attribute__((aligned(16))) char pool[2 * (2 * BM * BK + BN * BK) * 2];
  f32x4 acc[BM / 32][BN / 32];
  mgemm_acc<BM, BN, BK>(Ah, Al, Bth, K, acc, pool);
  const int tid = threadIdx.x;
  const int w = tid >> 6, lane = tid & 63;
  const int wm = w >> 1, wn = w & 1;
  const int kg = lane >> 4, lr = lane & 15;
  const int row0 = blockIdx.y * BM, col0 = blockIdx.x * BN;
#pragma unroll
  for (int fn = 0; fn < BN / 32; ++fn) {
    const int col = col0 + wn * (BN / 2) + fn * 16 + lr;
    const float bv = bias[col];
#pragma unroll
    for (int fm = 0; fm < BM / 32; ++fm) {
#pragma unroll
      for (int r = 0; r < 4; ++r) {
        const int row = row0 + wm * (BM / 2) + fm * 16 + kg * 4 + r;
        float v = acc[fm][fn][r] + bv;
        if (EPI == 0) {
          Cf[(size_t)row * N + col] = v;
        } else {
          float gl = 0.5f * v * (1.f + erff(v * 0.70710678118654752f));
          ushort_t h = f2bf(gl);
          Ch[(size_t)row * N + col] = h;
          Cl[(size_t)row * N + col] = f2bf(gl - bf2f(h));
        }
      }
    }
  }
}

// FF1 (GELU epilogue, BN=256) + folded weight-prep for the NEXT layer (blockIdx.y >= 32)
__global__ __launch_bounds__(256, 2) void ff1_fused(
    const ushort_t* __restrict__ Xh, const ushort_t* __restrict__ Xl,
    const ushort_t* __restrict__ W1th, const float* __restrict__ bias,
    ushort_t* __restrict__ Ch, ushort_t* __restrict__ Cl,
    const float* __restrict__ WqN, const float* __restrict__ WkN,
    const float* __restrict__ WvN, const float* __restrict__ WoN,
    const float* __restrict__ W1N, const float* __restrict__ W2N,
    ushort_t* __restrict__ WT4hN, ushort_t* __restrict__ W1thN, ushort_t* __restrict__ W2thN) {
  __shared__ __attribute__((aligned(16))) char pool[2 * (2 * 128 * 32 + 256 * 32) * 2];  // 64 KB
  if (blockIdx.y >= 32) {
    if (WqN == nullptr) return;
    const int wid = (blockIdx.y - 32) * 12 + blockIdx.x;
    wprep_dispatch((float(*)[65])pool, wid, WqN, WkN, WvN, WoN, W1N, W2N, WT4hN, W1thN, W2thN);
    return;
  }
  f32x4 acc[4][8];
  mgemm_acc<128, 256, 32>(Xh, Xl, W1th, H_, acc, pool);
  const int tid = threadIdx.x;
  const int w = tid >> 6, lane = tid & 63;
  const int wm = w >> 1, wn = w & 1;
  const int kg = lane >> 4, lr = lane & 15;
  const int row0 = blockIdx.y * 128, col0 = blockIdx.x * 256;
#pragma unroll
  for (int fn = 0; fn < 8; ++fn) {
    const int col = col0 + wn * 128 + fn * 16 + lr;
    const float bv = bias[col];
#pragma unroll
    for (int fm = 0; fm < 4; ++fm) {
#pragma unroll
      for (int r = 0; r < 4; ++r) {
        const int row = row0 + wm * 64 + fm * 16 + kg * 4 + r;
        float v = acc[fm][fn][r] + bv;
        float gl = 0.5f * v * (1.f + erff(v * 0.70710678118654752f));
        ushort_t h = f2bf(gl);
        Ch[(size_t)row * FF_ + col] = h;
        Cl[(size_t)row * FF_ + col] = f2bf(gl - bf2f(h));
      }
    }
  }
}

// ---------------- fused QKV: one block computes all 3 outputs, staging A once ----------------
__global__ __launch_bounds__(256) void qkv_m(const ushort_t* __restrict__ Xh, const ushort_t* __restrict__ Xl,
                      const ushort_t* __restrict__ WT4h,
                      const float* __restrict__ bq, const float* __restrict__ bk,
                      const float* __restrict__ bvv,
                      ushort_t* __restrict__ Qh, ushort_t* __restrict__ Ql,
                      ushort_t* __restrict__ Kh, ushort_t* __restrict__ Vth) {
  constexpr int ABYTES = 128 * 32 * 2;              // 8 KB per slice
  constexpr int BUF = 2 * ABYTES + 3 * ABYTES;      // 40 KB
  __shared__ __attribute__((aligned(16))) char pool[2 * BUF];   // 80 KB
  const int tid = threadIdx.x;
  const int w = tid >> 6, lane = tid & 63;
  const int wm = w >> 1, wn = w & 1;
  const int kgL = lane >> 4, lr = lane & 15;
  const int row0 = blockIdx.y * 128, col0 = blockIdx.x * 128;

  f32x4 acc[3][4][4];
#pragma unroll
  for (int z = 0; z < 3; ++z)
#pragma unroll
    for (int i = 0; i < 4; ++i)
#pragma unroll
      for (int j = 0; j < 4; ++j) acc[z][i][j] = (f32x4){0.f, 0.f, 0.f, 0.f};

  const int khL = kgL >> 1;
  const int swz = (((kgL & 1) ^ ((lr >> 2) & 1)) << 4);
  const int aB0 = khL * (128 * 32) + (wm * 64 + lr) * 32 + swz;
  const int bB0 = khL * (128 * 32) + (wn * 64 + lr) * 32 + swz;

  const ushort_t* gA_h = Xh + (size_t)row0 * H_;
  const ushort_t* gA_l = Xl + (size_t)row0 * H_;
  const ushort_t* gB0 = WT4h + (size_t)col0 * H_;
  const ushort_t* gB1 = WT4h + (size_t)H_ * H_ + (size_t)col0 * H_;
  const ushort_t* gB2 = WT4h + (size_t)2 * H_ * H_ + (size_t)col0 * H_;

  auto stageall = [&](int k0, char* buf) {
    stage_slice<128>(gA_h + k0, H_, buf);
    stage_slice<128>(gA_l + k0, H_, buf + ABYTES);
    stage_slice<128>(gB0 + k0, H_, buf + 2 * ABYTES);
    stage_slice<128>(gB1 + k0, H_, buf + 3 * ABYTES);
    stage_slice<128>(gB2 + k0, H_, buf + 4 * ABYTES);
  };

  const int nk = H_ / 32;   // 24
  stageall(0, pool);
  for (int k = 0; k < nk; ++k) {
    char* cur = pool + (k & 1) * BUF;
    if (k + 1 < nk) {
      stageall((k + 1) * 32, pool + ((k + 1) & 1) * BUF);
      asm volatile("s_waitcnt vmcnt(10)" ::: "memory");
    } else {
      asm volatile("s_waitcnt vmcnt(0)" ::: "memory");
    }
    __builtin_amdgcn_s_barrier();
    asm volatile("" ::: "memory");

    bf16x8 a_h[4], a_l[4];
#pragma unroll
    for (int fm = 0; fm < 4; ++fm) {
      a_h[fm] = *(const bf16x8*)(cur + aB0 + fm * 512);
      a_l[fm] = *(const bf16x8*)(cur + ABYTES + aB0 + fm * 512);
    }
#pragma unroll
    for (int z = 0; z < 3; ++z) {
      const char* bP = cur + (2 + z) * ABYTES;
      bf16x8 b_h[4];
#pragma unroll
      for (int fn = 0; fn < 4; ++fn) b_h[fn] = *(const bf16x8*)(bP + bB0 + fn * 512);
#pragma unroll
      for (int fm = 0; fm < 4; ++fm)
#pragma unroll
        for (int fn = 0; fn < 4; ++fn) {
          f32x4 c = acc[z][fm][fn];
          c = __builtin_amdgcn_mfma_f32_16x16x32_bf16(a_h[fm], b_h[fn], c, 0, 0, 0);
          c = __builtin_amdgcn_mfma_f32_16x16x32_bf16(a_l[fm], b_h[fn], c, 0, 0, 0);
          acc[z][fm][fn] = c;
        }
    }
    asm volatile("" ::: "memory");
    __builtin_amdgcn_s_barrier();
  }

  const int kg = kgL;
#pragma unroll
  for (int fn = 0; fn < 4; ++fn) {
    const int col = col0 + wn * 64 + fn * 16 + lr;
    const float bvq = bq[col], bvk = bk[col], bvv2 = bvv[col];
#pragma unroll
    for (int fm = 0; fm < 4; ++fm) {
      const int rowb = row0 + wm * 64 + fm * 16 + kg * 4;
#pragma unroll
      for (int r = 0; r < 4; ++r) {
        float v = acc[0][fm][fn][r] + bvq;
        ushort_t h = f2bf(v);
        Qh[(size_t)(rowb + r) * H_ + col] = h;
        Ql[(size_t)(rowb + r) * H_ + col] = f2bf(v - bf2f(h));
      }
#pragma unroll
      for (int r = 0; r < 4; ++r) {
        Kh[(size_t)(rowb + r) * H_ + col] = f2bf(acc[1][fm][fn][r] + bvk);
      }
      {
        us4 h4;
#pragma unroll
        for (int r = 0; r < 4; ++r) h4[r] = f2bf(acc[2][fm][fn][r] + bvv2);
        const int bb2 = rowb >> 8, s0 = rowb & 255;
        const int hh2 = col >> 6, d = col & 63;
        *(us4*)(Vth + ((size_t)(bb2 * NH_ + hh2) * DH_ + d) * S_ + s0) = h4;
      }
    }
  }
}

// ---------------- MFMA flash attention, double-buffered K/V ----------------
__global__ __launch_bounds__(256, 3) void attn_mfma(
    const ushort_t* __restrict__ Qh, const ushort_t* __restrict__ Ql,
    const ushort_t* __restrict__ Kh, const ushort_t* __restrict__ Vth,
    const int* __restrict__ amask,
    ushort_t* __restrict__ Oh, ushort_t* __restrict__ Ol) {
  const int bid = blockIdx.x;
  const int qt = bid / 192;
  const int gh = bid - qt * 192;
  const int b = gh / NH_;
  const int h = gh - b * NH_;
  __shared__ __attribute__((aligned(16))) ushort_t sKh[2][64 * 64];
  __shared__ __attribute__((aligned(16))) ushort_t sVh[2][64 * 64];
  __shared__ __attribute__((aligned(16))) unsigned sP[4][16 * 68];
  __shared__ float sBias[2][64];
  const int tid = threadIdx.x;
  const int w = tid >> 6, lane = tid & 63;
  const int kg = lane >> 4, lr = lane & 15;

  const int qrow = b * S_ + qt * 64 + w * 16 + lr;
  bf16x8 qfh[2], qfl[2];
#pragma unroll
  for (int ds2 = 0; ds2 < 2; ++ds2) {
    const size_t off = (size_t)qrow * H_ + h * DH_ + ds2 * 32 + kg * 8;
    qfh[ds2] = *(const bf16x8*)(Qh + off);
    qfl[ds2] = *(const bf16x8*)(Ql + off);
  }

  f32x4 ctx[4];
#pragma unroll
  for (int i = 0; i < 4; ++i) ctx[i] = (f32x4){0.f, 0.f, 0.f, 0.f};
  float mrow[4], lrw[4];
#pragma unroll
  for (int r = 0; r < 4; ++r) { mrow[r] = -1e30f; lrw[r] = 0.f; }

  unsigned* sPw = &sP[w][0];

  auto stageKV = [&](int kt, int bufi) {
#pragma unroll
    for (int i = 0; i < 2; ++i) {
      const int v = tid + i * 256;
      const int row = v >> 3;
      const int c16 = (v & 7) ^ (row & 7);
      const size_t kgl = (size_t)(b * S_ + kt * 64 + row) * H_ + h * DH_ + c16 * 8;
      gload16(Kh + kgl, (char*)&sKh[bufi][0] + v * 16);
      const size_t vgl = (size_t)((b * NH_ + h) * DH_ + row) * S_ + kt * 64 + c16 * 8;
      gload16(Vth + vgl, (char*)&sVh[bufi][0] + v * 16);
    }
    if (tid < 64) sBias[bufi][tid] = (amask[b * S_ + kt * 64 + tid] > 0) ? 0.f : -1e9f;
  };

  stageKV(0, 0);
  for (int kt = 0; kt < 4; ++kt) {
    const int bi = kt & 1;
    if (kt < 3) {
      stageKV(kt + 1, bi ^ 1);
      asm volatile("s_waitcnt vmcnt(4) lgkmcnt(0)" ::: "memory");
    } else {
      asm volatile("s_waitcnt vmcnt(0) lgkmcnt(0)" ::: "memory");
    }
    __builtin_amdgcn_s_barrier();
    asm volatile("" ::: "memory");

    // QK^T
    f32x4 sc[4];
#pragma unroll
    for (int kf = 0; kf < 4; ++kf) sc[kf] = (f32x4){0.f, 0.f, 0.f, 0.f};
#pragma unroll
    for (int kf = 0; kf < 4; ++kf) {
      const int krow = kf * 16 + lr;
#pragma unroll
      for (int ds2 = 0; ds2 < 2; ++ds2) {
        const int cb = (ds2 * 64 + kg * 16) ^ ((krow & 7) << 4);
        const bf16x8 kvh = *(const bf16x8*)((const char*)&sKh[bi][0] + krow * 128 + cb);
        sc[kf] = __builtin_amdgcn_mfma_f32_16x16x32_bf16(qfh[ds2], kvh, sc[kf], 0, 0, 0);
        sc[kf] = __builtin_amdgcn_mfma_f32_16x16x32_bf16(qfl[ds2], kvh, sc[kf], 0, 0, 0);
      }
    }
    float bsv[4];
#pragma unroll
    for (int kf = 0; kf < 4; ++kf) bsv[kf] = sBias[bi][kf * 16 + lr];

#pragma unroll
    for (int r = 0; r < 4; ++r) {
      float sv[4];
      float tmax = -1e30f;
#pragma unroll
      for (int kf = 0; kf < 4; ++kf) {
        sv[kf] = sc[kf][r] * 0.125f + bsv[kf];
        tmax = fmaxf(tmax, sv[kf]);
      }
#pragma unroll
      for (int o = 8; o > 0; o >>= 1) tmax = fmaxf(tmax, __shfl_xor(tmax, o, 64));
      const float mnew = fmaxf(mrow[r], tmax);
      const float corr = expf(mrow[r] - mnew);
      float ls = 0.f;
      const int qoff = (kg * 4 + r) * 68;
#pragma unroll
      for (int kf = 0; kf < 4; ++kf) {
        const float pe = expf(sv[kf] - mnew);
        ls += pe;
        const ushort_t hi = f2bf(pe);
        const ushort_t lo = f2bf(pe - bf2f(hi));
        sPw[qoff + kf * 16 + lr] = ((unsigned)hi << 16) | lo;
      }
#pragma unroll
      for (int o = 8; o > 0; o >>= 1) ls += __shfl_xor(ls, o, 64);
      lrw[r] = lrw[r] * corr + ls;
      mrow[r] = mnew;
#pragma unroll
      for (int df = 0; df < 4; ++df) ctx[df][r] *= corr;
    }

    // PV
#pragma unroll
    for (int ks = 0; ks < 2; ++ks) {
      unsigned w8[8];
      *(u32x4*)&w8[0] = *(const u32x4*)(sPw + lr * 68 + ks * 32 + kg * 8);
      *(u32x4*)&w8[4] = *(const u32x4*)(sPw + lr * 68 + ks * 32 + kg * 8 + 4);
      union { bf16x8 v; ushort_t u[8]; } ph, pl;
#pragma unroll
      for (int j = 0; j < 8; ++j) { ph.u[j] = (ushort_t)(w8[j] >> 16); pl.u[j] = (ushort_t)(w8[j] & 0xffffu); }
#pragma unroll
      for (int df = 0; df < 4; ++df) {
        const int vrow = df * 16 + lr;
        const int cb = (ks * 64 + kg * 16) ^ ((vrow & 7) << 4);
        const bf16x8 vvh = *(const bf16x8*)((const char*)&sVh[bi][0] + vrow * 128 + cb);
        ctx[df] = __builtin_amdgcn_mfma_f32_16x16x32_bf16(ph.v, vvh, ctx[df], 0, 0, 0);
        ctx[df] = __builtin_amdgcn_mfma_f32_16x16x32_bf16(pl.v, vvh, ctx[df], 0, 0, 0);
      }
    }
    asm volatile("" ::: "memory");
    __builtin_amdgcn_s_barrier();
  }

#pragma unroll
  for (int r = 0; r < 4; ++r) {
    const float inv = 1.f / lrw[r];
    const int tok = b * S_ + qt * 64 + w * 16 + kg * 4 + r;
#pragma unroll
    for (int df = 0; df < 4; ++df) {
      const float v = ctx[df][r] * inv;
      const ushort_t hi = f2bf(v);
      const size_t o = (size_t)tok * H_ + h * DH_ + df * 16 + lr;
      Oh[o] = hi;
      Ol[o] = f2bf(v - bf2f(hi));
    }
  }
}

// ---------------- CRF v4: LDS wave-local broadcast (bit-identical math to v3) ----------------
__global__ __launch_bounds__(128) void crf_kernel(const float* __restrict__ emis, const int* __restrict__ tags,
                          const int* __restrict__ amask,
                          const float* __restrict__ crf_start, const float* __restrict__ crf_end,
                          const float* __restrict__ trans,
                          float* __restrict__ partial, float* __restrict__ out) {
  const int b = blockIdx.x;
  const int tid = threadIdx.x;
  const int wv = tid >> 6;
  const int lane = tid & 63;
  __shared__ float sE[S_ * T_];
  __shared__ float sM[S_];
  __shared__ float trs[T_ * T_];
  __shared__ unsigned char hist[S_ - 1][16];
  __shared__ float pathf[S_];
  __shared__ __attribute__((aligned(16))) float sBr[2][16];
  for (int i = tid; i < S_ * T_; i += 128) {
    const int s = i / T_, t = i - s * T_;
    sE[i] = emis[((size_t)s * B_ + b) * T_ + t];
  }
  for (int i = tid; i < S_; i += 128) sM[i] = (float)amask[b * S_ + i];
  for (int i = tid; i < T_ * T_; i += 128) trs[i] = trans[i];
  __syncthreads();

  const int t = lane;
  const bool act = t < T_;
  float trc[T_];
#pragma unroll
  for (int p = 0; p < T_; ++p) trc[p] = act ? trs[p * T_ + t] : 0.f;

  if (wv == 0) {
    float alpha = act ? crf_start[t] + sE[t] : 0.f;
    for (int s = 1; s < S_; ++s) {
      if (act) sBr[0][t] = alpha;
      asm volatile("s_waitcnt lgkmcnt(0)" ::: "memory");
      float ap[12];
      *(f32x4*)&ap[0] = *(const f32x4*)&sBr[0][0];
      *(f32x4*)&ap[4] = *(const f32x4*)&sBr[0][4];
      ap[8] = sBr[0][8];
      if (act) {
        const float e = sE[s * T_ + t];
        float v[T_];
#pragma unroll
        for (int p = 0; p < T_; ++p) v[p] = ap[p] + trc[p];
        // max is order-exact: tree form
        float m0 = fmaxf(fmaxf(v[0], v[1]), fmaxf(v[2], v[3]));
        float m1 = fmaxf(fmaxf(v[4], v[5]), fmaxf(v[6], v[7]));
        const float mx = fmaxf(fmaxf(m0, m1), v[8]);
        // keep p-ascending chain (bit-identical to v3)
        float sum = 0.f;
#pragma unroll
        for (int p = 0; p < T_; ++p) sum += __expf(v[p] - mx);
        const float na = mx + __logf(sum) + e;
        if (sM[s] > 0.f) alpha = na;
      }
    }
    float nsum = 0.f;
    int len = 0;
#pragma unroll
    for (int j = 0; j < 4; ++j) {
      const int s = lane + j * 64;
      const int mk = (sM[s] > 0.f) ? 1 : 0;
      len += mk;
      if (s >= 1 && mk) {
        const int tc = tags[b * S_ + s], tp = tags[b * S_ + s - 1];
        nsum += trs[tp * T_ + tc] + sE[s * T_ + tc];
      }
    }
#pragma unroll
    for (int o = 32; o > 0; o >>= 1) {
      nsum += __shfl_xor(nsum, o, 64);
      len += __shfl_xor(len, o, 64);
    }
    if (act) sBr[0][t] = alpha + crf_end[t];
    asm volatile("s_waitcnt lgkmcnt(0)" ::: "memory");
    if (lane == 0) {
      float zp[T_];
#pragma unroll
      for (int p = 0; p < T_; ++p) zp[p] = sBr[0][p];
      float mx = -1e30f;
#pragma unroll
      for (int p = 0; p < T_; ++p) mx = fmaxf(mx, zp[p]);
      float sum = 0.f;
#pragma unroll
      for (int p = 0; p < T_; ++p) sum += __expf(zp[p] - mx);
      const float logZ = mx + __logf(sum);
      const int tg0 = tags[b * S_];
      const float score = nsum + crf_start[tg0] + sE[tg0] + crf_end[tags[b * S_ + len - 1]];
      partial[b] = score - logZ;
    }
  } else {
    float vit = act ? crf_start[t] + sE[t] : 0.f;
    for (int s = 1; s < S_; ++s) {
      if (act) sBr[1][t] = vit;
      asm volatile("s_waitcnt lgkmcnt(0)" ::: "memory");
      float vp[12];
      *(f32x4*)&vp[0] = *(const f32x4*)&sBr[1][0];
      *(f32x4*)&vp[4] = *(const f32x4*)&sBr[1][4];
      vp[8] = sBr[1][8];
      if (act) {
        const float e = sE[s * T_ + t];
        float best = -1e30f; int bi = 0;
#pragma unroll
        for (int p = 0; p < T_; ++p) {
          const float scv = vp[p] + trc[p];
          if (scv > best) { best = scv; bi = p; }
        }
        if (sM[s] > 0.f) {
          vit = best + e;
          hist[s - 1][t] = (unsigned char)bi;
        } else {
          hist[s - 1][t] = (unsigned char)t;
        }
      }
    }
    if (act) sBr[1][t] = vit + crf_end[t];
    asm volatile("s_waitcnt lgkmcnt(0)" ::: "memory");
    if (lane == 0) {
      float best = -1e30f; int lastTag = 0;
#pragma unroll
      for (int p = 0; p < T_; ++p) {
        const float wpv = sBr[1][p];
        if (wpv > best) { best = wpv; lastTag = p; }
      }
      int tc = lastTag;
      pathf[S_ - 1] = (float)tc;
      for (int i = S_ - 2; i >= 0; --i) {
        tc = hist[i][tc];
        pathf[i] = (float)tc;
      }
    }
  }
  __syncthreads();
#pragma unroll
  for (int j = 0; j < 2; ++j) {
    const int s = tid + j * 128;
    out[1 + b * S_ + s] = pathf[s];
  }
}

__global__ __launch_bounds__(64) void crf_final(const float* __restrict__ partial, float* __restrict__ out) {
  const int lane = threadIdx.x;
  float v = (lane < B_) ? partial[lane] : 0.f;
#pragma unroll
  for (int o = 32; o > 0; o >>= 1) v += __shfl_xor(v, o, 64);
  if (lane == 0) out[0] = -(v * (1.f / B_));
}

extern "C" void kernel_launch(void* const* d_in, const int* in_sizes, int n_in,
                              void* d_out, int out_size, void* d_ws, size_t ws_size,
                              hipStream_t stream) {
  const int* input_ids = (const int*)d_in[0];
  const int* token_type_ids = (const int*)d_in[1];
  const int* attention_mask = (const int*)d_in[2];
  const int* tags = (const int*)d_in[3];
  const float* word_emb = (const float*)d_in[4];
  const float* pos_emb = (const float*)d_in[5];
  const float* type_emb = (const float*)d_in[6];
  const float* emb_ln_g = (const float*)d_in[7];
  const float* emb_ln_b = (const float*)d_in[8];
  const float* Wq = (const float*)d_in[9];
  const float* bq = (const float*)d_in[10];
  const float* Wk = (const float*)d_in[11];
  const float* bk = (const float*)d_in[12];
  const float* Wv = (const float*)d_in[13];
  const float* bv = (const float*)d_in[14];
  const float* Wo = (const float*)d_in[15];
  const float* bo = (const float*)d_in[16];
  const float* ln1_g = (const float*)d_in[17];
  const float* ln1_b = (const float*)d_in[18];
  const float* W1 = (const float*)d_in[19];
  const float* b1 = (const float*)d_in[20];
  const float* W2 = (const float*)d_in[21];
  const float* b2 = (const float*)d_in[22];
  const float* ln2_g = (const float*)d_in[23];
  const float* ln2_b = (const float*)d_in[24];
  const float* dense_W = (const float*)d_in[25];
  const float* dense_b = (const float*)d_in[26];
  const float* crf_start = (const float*)d_in[27];
  const float* crf_end = (const float*)d_in[28];
  const float* crf_trans = (const float*)d_in[29];

  constexpr size_t NTOK = (size_t)B_ * S_;        // 4096
  constexpr size_t XSZ = NTOK * H_;               // 3,145,728
  constexpr size_t WT4SZ = (size_t)4 * H_ * H_;   // 2,359,296
  constexpr size_t WFSZ = (size_t)H_ * FF_;       // 2,359,296

  char* p = (char*)d_ws;
  float* X = (float*)p;            p += XSZ * 4;
  float* TMP = (float*)p;          p += XSZ * 4;
  char* UN = p;                    p += 8 * XSZ * 2;     // 50.33 MB union
  ushort_t* Qh = (ushort_t*)UN;
  ushort_t* Ql = Qh + XSZ;
  ushort_t* Kh = Ql + XSZ;
  ushort_t* Vth = Kh + XSZ;
  ushort_t* CTXh = Vth + XSZ;
  ushort_t* CTXl = CTXh + XSZ;
  ushort_t* FFh = (ushort_t*)UN;                        // aliases QKV after dead
  ushort_t* FFl = FFh + NTOK * FF_;
  ushort_t* Xh = (ushort_t*)p;     p += XSZ * 2;
  ushort_t* Xl = (ushort_t*)p;     p += XSZ * 2;
  ushort_t* WT4h2 = (ushort_t*)p;  p += WT4SZ * 2 * 2;  // double-buffered
  ushort_t* W1th2 = (ushort_t*)p;  p += WFSZ * 2 * 2;
  ushort_t* W2th2 = (ushort_t*)p;  p += WFSZ * 2 * 2;
  float* EM = (float*)p;           p += (size_t)S_ * B_ * T_ * 4;
  float* PART = (float*)p;         p += B_ * 4;

  emb_ln_kernel<<<dim3(4096), dim3(256), 0, stream>>>(input_ids, token_type_ids, word_emb, pos_emb,
                                                      type_emb, emb_ln_g, emb_ln_b, X, Xh, Xl);
  // layer 0 weights into parity 0
  wprep_k<<<dim3(1728), dim3(256), 0, stream>>>(Wq, Wk, Wv, Wo, W1, W2, WT4h2, W1th2, W2th2);

  for (int l = 0; l < L_; ++l) {
    const int pr = l & 1, pn = (l + 1) & 1;
    ushort_t* WT4h = WT4h2 + (size_t)pr * WT4SZ;
    ushort_t* W1th = W1th2 + (size_t)pr * WFSZ;
    ushort_t* W2th = W2th2 + (size_t)pr * WFSZ;
    const bool hasNext = (l + 1 < L_);
    const size_t wo_n = (size_t)(l + 1) * H_ * H_;

    qkv_m<<<dim3(6, 32), dim3(256), 0, stream>>>(Xh, Xl, WT4h, bq + (size_t)l * H_,
                                                 bk + (size_t)l * H_, bv + (size_t)l * H_,
                                                 Qh, Ql, Kh, Vth);
    attn_mfma<<<dim3(768), dim3(256), 0, stream>>>(Qh, Ql, Kh, Vth, attention_mask, CTXh, CTXl);
    mgemm<128, 128, 32, 0><<<dim3(6, 32), dim3(256), 0, stream>>>(
        CTXh, CTXl, WT4h + (size_t)3 * H_ * H_,
        bo + (size_t)l * H_, TMP, nullptr, nullptr, H_, H_);
    ln_kernel<<<dim3(4096), dim3(256), 0, stream>>>(X, TMP, ln1_g + (size_t)l * H_,
                                                    ln1_b + (size_t)l * H_, X, Xh, Xl);
    ff1_fused<<<dim3(12, 32 + 144), dim3(256), 0, stream>>>(
        Xh, Xl, W1th, b1 + (size_t)l * FF_, FFh, FFl,
        hasNext ? Wq + wo_n : nullptr, Wk + wo_n, Wv + wo_n, Wo + wo_n,
        W1 + (size_t)(l + 1) * WFSZ, W2 + (size_t)(l + 1) * WFSZ,
        WT4h2 + (size_t)pn * WT4SZ, W1th2 + (size_t)pn * WFSZ, W2th2 + (size_t)pn * WFSZ);
    mgemm<128, 128, 32, 0><<<dim3(6, 32), dim3(256), 0, stream>>>(
        FFh, FFl, W2th, b2 + (size_t)l * H_, TMP, nullptr, nullptr, H_, FF_);
    if (l + 1 < L_) {
      ln_kernel<<<dim3(4096), dim3(256), 0, stream>>>(X, TMP, ln2_g + (size_t)l * H_,
                                                      ln2_b + (size_t)l * H_, X, Xh, Xl);
    } else {
      ln_emis_kernel<<<dim3(4096), dim3(256), 0, stream>>>(X, TMP, ln2_g + (size_t)l * H_,
                                                           ln2_b + (size_t)l * H_, dense_W,
                                                           dense_b, EM);
    }
  }

  crf_kernel<<<dim3(B_), dim3(128), 0, stream>>>(EM, tags, attention_mask, crf_start, crf_end,
                                                 crf_trans, PART, (float*)d_out);
  crf_final<<<dim3(1), dim3(64), 0, stream>>>(PART, (float*)d_out);
}

// Round 14
// 3110.153 us; speedup vs baseline: 1.0173x; 1.0173x over previous
//
#include <hip/hip_runtime.h>
#include <math.h>

#define B_ 16
#define S_ 256
#define H_ 768
#define L_ 12
#define NH_ 12
#define DH_ 64
#define FF_ 3072
#define T_ 9

typedef unsigned short ushort_t;
typedef __attribute__((ext_vector_type(8))) __bf16 bf16x8;
typedef __attribute__((ext_vector_type(4))) float f32x4;
typedef __attribute__((ext_vector_type(4))) unsigned short us4;
typedef __attribute__((ext_vector_type(4))) unsigned int u32x4;

__device__ __forceinline__ ushort_t f2bf(float f) {
  union { float f; unsigned u; } v; v.f = f;
  unsigned r = v.u + 0x7FFFu + ((v.u >> 16) & 1u);
  return (ushort_t)(r >> 16);
}
__device__ __forceinline__ float bf2f(ushort_t h) {
  union { unsigned u; float f; } v; v.u = ((unsigned)h) << 16;
  return v.f;
}
__device__ __forceinline__ float rdlane(float v, int l) {
  union { float f; int i; } u; u.f = v;
  union { int i; float f; } o; o.i = __builtin_amdgcn_readlane(u.i, l);
  return o.f;
}
__device__ __forceinline__ void gload16(const void* g, void* l) {
  __builtin_amdgcn_global_load_lds((const __attribute__((address_space(1))) void*)g,
                                   (__attribute__((address_space(3))) void*)l, 16, 0, 0);
}

// ---------------- fused embedding sum + layernorm (hi/lo out only) ----------------
__global__ __launch_bounds__(256) void emb_ln_kernel(const int* __restrict__ ids, const int* __restrict__ tt,
                              const float* __restrict__ we, const float* __restrict__ pe,
                              const float* __restrict__ te, const float* __restrict__ g,
                              const float* __restrict__ bb,
                              ushort_t* __restrict__ oh, ushort_t* __restrict__ ol) {
  const int token = blockIdx.x;
  const int tid = threadIdx.x;
  const int s = token & (S_ - 1);
  const int id = ids[token];
  const int t2 = tt[token];
  float x[3];
  float sum = 0.f;
#pragma unroll
  for (int i = 0; i < 3; ++i) {
    int d = tid + i * 256;
    x[i] = we[(size_t)id * H_ + d] + pe[(size_t)s * H_ + d] + te[(size_t)t2 * H_ + d];
    sum += x[i];
  }
  __shared__ float red[4];
#pragma unroll
  for (int o = 32; o > 0; o >>= 1) sum += __shfl_xor(sum, o, 64);
  const int wid = tid >> 6, lane = tid & 63;
  if (lane == 0) red[wid] = sum;
  __syncthreads();
  const float mean = (red[0] + red[1] + red[2] + red[3]) * (1.f / H_);
  float vs = 0.f;
#pragma unroll
  for (int i = 0; i < 3; ++i) { float dv = x[i] - mean; vs += dv * dv; }
#pragma unroll
  for (int o = 32; o > 0; o >>= 1) vs += __shfl_xor(vs, o, 64);
  __syncthreads();
  if (lane == 0) red[wid] = vs;
  __syncthreads();
  const float var = (red[0] + red[1] + red[2] + red[3]) * (1.f / H_);
  const float inv = rsqrtf(var + 1e-12f);
  ushort_t* hp = oh + (size_t)token * H_;
  ushort_t* lp = ol + (size_t)token * H_;
#pragma unroll
  for (int i = 0; i < 3; ++i) {
    int d = tid + i * 256;
    float y = (x[i] - mean) * inv * g[d] + bb[d];
    ushort_t h = f2bf(y);
    hp[d] = h;
    lp[d] = f2bf(y - bf2f(h));
  }
}

// ---------------- layernorm: base from hi/lo pair + f32 delta -> hi/lo out (in-place ok) ----------------
__global__ __launch_bounds__(256) void ln_kernel(const ushort_t* __restrict__ bh, const ushort_t* __restrict__ bl,
                          const float* __restrict__ delta,
                          const float* __restrict__ g, const float* __restrict__ bb,
                          ushort_t* __restrict__ oh, ushort_t* __restrict__ ol) {
  const int token = blockIdx.x;
  const int tid = threadIdx.x;
  const ushort_t* bhp = bh + (size_t)token * H_;
  const ushort_t* blp = bl + (size_t)token * H_;
  const float* dp = delta + (size_t)token * H_;
  float x[3];
  float s = 0.f;
#pragma unroll
  for (int i = 0; i < 3; ++i) {
    int d = tid + i * 256;
    x[i] = bf2f(bhp[d]) + bf2f(blp[d]) + dp[d];
    s += x[i];
  }
  __shared__ float red[4];
#pragma unroll
  for (int o = 32; o > 0; o >>= 1) s += __shfl_xor(s, o, 64);
  const int wid = tid >> 6, lane = tid & 63;
  if (lane == 0) red[wid] = s;
  __syncthreads();
  const float mean = (red[0] + red[1] + red[2] + red[3]) * (1.f / H_);
  float vs = 0.f;
#pragma unroll
  for (int i = 0; i < 3; ++i) { float dv = x[i] - mean; vs += dv * dv; }
#pragma unroll
  for (int o = 32; o > 0; o >>= 1) vs += __shfl_xor(vs, o, 64);
  __syncthreads();
  if (lane == 0) red[wid] = vs;
  __syncthreads();
  const float var = (red[0] + red[1] + red[2] + red[3]) * (1.f / H_);
  const float inv = rsqrtf(var + 1e-12f);
  ushort_t* hp = oh + (size_t)token * H_;
  ushort_t* lp = ol + (size_t)token * H_;
#pragma unroll
  for (int i = 0; i < 3; ++i) {
    int d = tid + i * 256;
    float y = (x[i] - mean) * inv * g[d] + bb[d];
    ushort_t h = f2bf(y);
    hp[d] = h;
    lp[d] = f2bf(y - bf2f(h));
  }
}

// ---------------- final layernorm + emissions fused ----------------
__global__ __launch_bounds__(256) void ln_emis_kernel(const ushort_t* __restrict__ bh, const ushort_t* __restrict__ bl,
                               const float* __restrict__ delta,
                               const float* __restrict__ g, const float* __restrict__ bb,
                               const float* __restrict__ W, const float* __restrict__ wbias,
                               float* __restrict__ E) {
  const int token = blockIdx.x;
  const int tid = threadIdx.x;
  __shared__ float sW[H_ * T_];     // 27 KB
  __shared__ float red[4];
  __shared__ float wred[4][12];
  for (int i = tid; i < H_ * T_; i += 256) sW[i] = W[i];

  const ushort_t* bhp = bh + (size_t)token * H_;
  const ushort_t* blp = bl + (size_t)token * H_;
  const float* dp = delta + (size_t)token * H_;
  float x[3];
  float s = 0.f;
#pragma unroll
  for (int i = 0; i < 3; ++i) {
    int d = tid + i * 256;
    x[i] = bf2f(bhp[d]) + bf2f(blp[d]) + dp[d];
    s += x[i];
  }
#pragma unroll
  for (int o = 32; o > 0; o >>= 1) s += __shfl_xor(s, o, 64);
  const int wid = tid >> 6, lane = tid & 63;
  if (lane == 0) red[wid] = s;
  __syncthreads();
  const float mean = (red[0] + red[1] + red[2] + red[3]) * (1.f / H_);
  float vs = 0.f;
#pragma unroll
  for (int i = 0; i < 3; ++i) { float dv = x[i] - mean; vs += dv * dv; }
#pragma unroll
  for (int o = 32; o > 0; o >>= 1) vs += __shfl_xor(vs, o, 64);
  __syncthreads();
  if (lane == 0) red[wid] = vs;
  __syncthreads();
  const float var = (red[0] + red[1] + red[2] + red[3]) * (1.f / H_);
  const float inv = rsqrtf(var + 1e-12f);

  float acc9[T_];
#pragma unroll
  for (int t = 0; t < T_; ++t) acc9[t] = 0.f;
#pragma unroll
  for (int i = 0; i < 3; ++i) {
    int d = tid + i * 256;
    float y = (x[i] - mean) * inv * g[d] + bb[d];
    const float* wr = sW + d * T_;
#pragma unroll
    for (int t = 0; t < T_; ++t) acc9[t] = fmaf(y, wr[t], acc9[t]);
  }
#pragma unroll
  for (int o = 32; o > 0; o >>= 1)
#pragma unroll
    for (int t = 0; t < T_; ++t) acc9[t] += __shfl_xor(acc9[t], o, 64);
  if (lane == 0) {
#pragma unroll
    for (int t = 0; t < T_; ++t) wred[wid][t] = acc9[t];
  }
  __syncthreads();
  if (tid < T_) {
    const float v = wred[0][tid] + wred[1][tid] + wred[2][tid] + wred[3][tid] + wbias[tid];
    const int b2 = token >> 8, s2 = token & 255;
    E[((size_t)s2 * B_ + b2) * T_ + tid] = v;
  }
}

// ---------------- weight transpose + bf16 round: src[K][N] f32 -> dst[N][K] ----------------
__device__ __forceinline__ void transpose_core(float (*t)[65], const float* __restrict__ src,
                                               ushort_t* __restrict__ dh,
                                               int K, int N, int n0, int k0) {
  const int tid = threadIdx.x;
#pragma unroll
  for (int i = 0; i < 16; ++i) {
    int lin = tid + i * 256;
    int kk = lin >> 6, nn = lin & 63;
    t[kk][nn] = src[(size_t)(k0 + kk) * N + n0 + nn];
  }
  __syncthreads();
#pragma unroll
  for (int i = 0; i < 16; ++i) {
    int lin = tid + i * 256;
    int nn = lin >> 6, kk = lin & 63;
    dh[(size_t)(n0 + nn) * K + k0 + kk] = f2bf(t[kk][nn]);
  }
}

__device__ __forceinline__ void wprep_dispatch(float (*t)[65], int wid,
                        const float* Wq, const float* Wk, const float* Wv, const float* Wo,
                        const float* W1, const float* W2,
                        ushort_t* WT4h, ushort_t* W1th, ushort_t* W2th) {
  if (wid < 576) {
    const int z = wid / 144, r = wid - z * 144;
    const int x = r % 12, y = r / 12;
    const float* src = z == 0 ? Wq : (z == 1 ? Wk : (z == 2 ? Wv : Wo));
    transpose_core(t, src, WT4h + (size_t)z * H_ * H_, H_, H_, x * 64, y * 64);
  } else if (wid < 1152) {
    const int i = wid - 576;
    const int x = i % 48, y = i / 48;
    transpose_core(t, W1, W1th, H_, FF_, x * 64, y * 64);
  } else {
    const int i = wid - 1152;
    const int x = i % 12, y = i / 12;
    transpose_core(t, W2, W2th, FF_, H_, x * 64, y * 64);
  }
}

__global__ __launch_bounds__(256) void wprep_k(const float* __restrict__ Wq, const float* __restrict__ Wk,
                        const float* __restrict__ Wv, const float* __restrict__ Wo,
                        const float* __restrict__ W1, const float* __restrict__ W2,
                        ushort_t* __restrict__ WT4h,
                        ushort_t* __restrict__ W1th, ushort_t* __restrict__ W2th) {
  __shared__ float t[64][65];
  wprep_dispatch(t, blockIdx.x, Wq, Wk, Wv, Wo, W1, W2, WT4h, W1th, W2th);
}

// ---------------- conflict-free staging (proven mapping), one 32-K slice ----------------
template <int R>
__device__ __forceinline__ void stage_slice(const ushort_t* __restrict__ gsrc, int K, char* lds) {
  const int tid = threadIdx.x;
  constexpr int NIT = (R * 4) / 256;
#pragma unroll
  for (int i = 0; i < NIT; ++i) {
    const int v = tid + i * 256;
    const int kh = v / (2 * R);
    const int r2 = v & (2 * R - 1);
    const int row = r2 >> 1;
    const int kg = (kh << 1) | ((r2 & 1) ^ ((row >> 2) & 1));
    gload16(gsrc + (size_t)row * K + kg * 8, lds + (i * 256 + (tid & 192)) * 16);
  }
}

// ---------------- split-A MFMA GEMM core, double-buffered: acc = (Ah+Al) * Bh^T ----------------
template <int BM, int BN, int BK>
__device__ __forceinline__ void mgemm_acc(
    const ushort_t* __restrict__ Ah, const ushort_t* __restrict__ Al,
    const ushort_t* __restrict__ Bth,
    int K, f32x4 (&acc)[BM / 32][BN / 32], char* pool) {
  constexpr int FM = BM / 32;
  constexpr int FN = BN / 32;
  constexpr int ABYTES = BM * BK * 2;
  constexpr int BBYTES = BN * BK * 2;
  constexpr int BUF = 2 * ABYTES + BBYTES;
  constexpr int NL = (8 * BM + 4 * BN) / 256;
  const int tid = threadIdx.x;
  const int w = tid >> 6, lane = tid & 63;
  const int wm = w >> 1, wn = w & 1;
  const int kgL = lane >> 4, lr = lane & 15;
  const int row0 = blockIdx.y * BM, col0 = blockIdx.x * BN;

#pragma unroll
  for (int i = 0; i < FM; ++i)
#pragma unroll
    for (int j = 0; j < FN; ++j) acc[i][j] = (f32x4){0.f, 0.f, 0.f, 0.f};

  const int khL = kgL >> 1;
  const int swz = (((kgL & 1) ^ ((lr >> 2) & 1)) << 4);
  const int aB0 = khL * (BM * 32) + (wm * (BM / 2) + lr) * 32 + swz;
  const int bB0 = khL * (BN * 32) + (wn * (BN / 2) + lr) * 32 + swz;

  const ushort_t* gA_h = Ah + (size_t)row0 * K;
  const ushort_t* gA_l = Al + (size_t)row0 * K;
  const ushort_t* gB_h = Bth + (size_t)col0 * K;

  auto stageall = [&](int k0, char* buf) {
#pragma unroll
    for (int c = 0; c < BK / 32; ++c) {
      stage_slice<BM>(gA_h + k0 + c * 32, K, buf + c * BM * 64);
      stage_slice<BM>(gA_l + k0 + c * 32, K, buf + ABYTES + c * BM * 64);
      stage_slice<BN>(gB_h + k0 + c * 32, K, buf + 2 * ABYTES + c * BN * 64);
    }
  };

  const int nk = K / BK;
  stageall(0, pool);
  for (int k = 0; k < nk; ++k) {
    char* cur = pool + (k & 1) * BUF;
    if (k + 1 < nk) {
      stageall((k + 1) * BK, pool + ((k + 1) & 1) * BUF);
      if constexpr (NL == 6) {
        asm volatile("s_waitcnt vmcnt(6)" ::: "memory");
      } else if constexpr (NL == 8) {
        asm volatile("s_waitcnt vmcnt(8)" ::: "memory");
      } else {
        asm volatile("s_waitcnt vmcnt(0)" ::: "memory");
      }
    } else {
      asm volatile("s_waitcnt vmcnt(0)" ::: "memory");
    }
    __builtin_amdgcn_s_barrier();
    asm volatile("" ::: "memory");

#pragma unroll
    for (int ks = 0; ks < BK / 32; ++ks) {
      const char* aP = cur + ks * BM * 64;
      const char* bP = cur + 2 * ABYTES + ks * BN * 64;
      bf16x8 a_h[FM], a_l[FM], b_h[FN];
#pragma unroll
      for (int fm = 0; fm < FM; ++fm) {
        a_h[fm] = *(const bf16x8*)(aP + aB0 + fm * 512);
        a_l[fm] = *(const bf16x8*)(aP + ABYTES + aB0 + fm * 512);
      }
#pragma unroll
      for (int fn = 0; fn < FN; ++fn) {
        b_h[fn] = *(const bf16x8*)(bP + bB0 + fn * 512);
      }
#pragma unroll
      for (int fm = 0; fm < FM; ++fm)
#pragma unroll
        for (int fn = 0; fn < FN; ++fn) {
          f32x4 c = acc[fm][fn];
          c = __builtin_amdgcn_mfma_f32_16x16x32_bf16(a_h[fm], b_h[fn], c, 0, 0, 0);
          c = __builtin_amdgcn_mfma_f32_16x16x32_bf16(a_l[fm], b_h[fn], c, 0, 0, 0);
          acc[fm][fn] = c;
        }
    }
    asm volatile("" ::: "memory");
    __builtin_amdgcn_s_barrier();
  }
}

// generic GEMM, EPI 0: f32 out
template <int BM, int BN, int BK, int EPI>
__global__ __launch_bounds__(256, 3) void mgemm(const ushort_t* __restrict__ Ah, const ushort_t* __restrict__ Al,
                      const ushort_t* __restrict__ Bth,
                      const float* __restrict__ bias, float* __restrict__ Cf,
                      ushort_t* __restrict__ Ch, ushort_t* __restrict__ Cl, int N, int K) {
  __shared__ __attribute__((aligned(16))) char pool[2 * (2 * BM * BK + BN * BK) * 2];
  f32x4 acc[BM / 32][BN / 32];
  mgemm_acc<BM, BN, BK>(Ah, Al, Bth, K, acc, pool);
  const int tid = threadIdx.x;
  const int w = tid >> 6, lane = tid & 63;
  const int wm = w >> 1, wn = w & 1;
  const int kg = lane >> 4, lr = lane & 15;
  const int row0 = blockIdx.y * BM, col0 = blockIdx.x * BN;
#pragma unroll
  for (int fn = 0; fn < BN / 32; ++fn) {
    const int col = col0 + wn * (BN / 2) + fn * 16 + lr;
    const float bv = bias[col];
#pragma unroll
    for (int fm = 0; fm < BM / 32; ++fm) {
#pragma unroll
      for (int r = 0; r < 4; ++r) {
        const int row = row0 + wm * (BM / 2) + fm * 16 + kg * 4 + r;
        float v = acc[fm][fn][r] + bv;
        if (EPI == 0) {
          Cf[(size_t)row * N + col] = v;
        } else {
          float gl = 0.5f * v * (1.f + erff(v * 0.70710678118654752f));
          ushort_t h = f2bf(gl);
          Ch[(size_t)row * N + col] = h;
          Cl[(size_t)row * N + col] = f2bf(gl - bf2f(h));
        }
      }
    }
  }
}

// FF1 (GELU epilogue, BN=256) + folded weight-prep for the NEXT layer (blockIdx.y >= 32)
__global__ __launch_bounds__(256, 2) void ff1_fused(
    const ushort_t* __restrict__ Xh, const ushort_t* __restrict__ Xl,
    const ushort_t* __restrict__ W1th, const float* __restrict__ bias,
    ushort_t* __restrict__ Ch, ushort_t* __restrict__ Cl,
    const float* __restrict__ WqN, const float* __restrict__ WkN,
    const float* __restrict__ WvN, const float* __restrict__ WoN,
    const float* __restrict__ W1N, const float* __restrict__ W2N,
    ushort_t* __restrict__ WT4hN, ushort_t* __restrict__ W1thN, ushort_t* __restrict__ W2thN) {
  __shared__ __attribute__((aligned(16))) char pool[2 * (2 * 128 * 32 + 256 * 32) * 2];  // 64 KB
  if (blockIdx.y >= 32) {
    if (WqN == nullptr) return;
    const int wid = (blockIdx.y - 32) * 12 + blockIdx.x;
    wprep_dispatch((float(*)[65])pool, wid, WqN, WkN, WvN, WoN, W1N, W2N, WT4hN, W1thN, W2thN);
    return;
  }
  f32x4 acc[4][8];
  mgemm_acc<128, 256, 32>(Xh, Xl, W1th, H_, acc, pool);
  const int tid = threadIdx.x;
  const int w = tid >> 6, lane = tid & 63;
  const int wm = w >> 1, wn = w & 1;
  const int kg = lane >> 4, lr = lane & 15;
  const int row0 = blockIdx.y * 128, col0 = blockIdx.x * 256;
#pragma unroll
  for (int fn = 0; fn < 8; ++fn) {
    const int col = col0 + wn * 128 + fn * 16 + lr;
    const float bv = bias[col];
#pragma unroll
    for (int fm = 0; fm < 4; ++fm) {
#pragma unroll
      for (int r = 0; r < 4; ++r) {
        const int row = row0 + wm * 64 + fm * 16 + kg * 4 + r;
        float v = acc[fm][fn][r] + bv;
        float gl = 0.5f * v * (1.f + erff(v * 0.70710678118654752f));
        ushort_t h = f2bf(gl);
        Ch[(size_t)row * FF_ + col] = h;
        Cl[(size_t)row * FF_ + col] = f2bf(gl - bf2f(h));
      }
    }
  }
}

// ---------------- fused QKV: one block computes all 3 outputs, staging A once ----------------
__global__ __launch_bounds__(256) void qkv_m(const ushort_t* __restrict__ Xh, const ushort_t* __restrict__ Xl,
                      const ushort_t* __restrict__ WT4h,
                      const float* __restrict__ bq, const float* __restrict__ bk,
                      const float* __restrict__ bvv,
                      ushort_t* __restrict__ Qh, ushort_t* __restrict__ Ql,
                      ushort_t* __restrict__ Kh, ushort_t* __restrict__ Vth) {
  constexpr int ABYTES = 128 * 32 * 2;
  constexpr int BUF = 2 * ABYTES + 3 * ABYTES;      // 40 KB
  __shared__ __attribute__((aligned(16))) char pool[2 * BUF];   // 80 KB
  const int tid = threadIdx.x;
  const int w = tid >> 6, lane = tid & 63;
  const int wm = w >> 1, wn = w & 1;
  const int kgL = lane >> 4, lr = lane & 15;
  const int row0 = blockIdx.y * 128, col0 = blockIdx.x * 128;

  f32x4 acc[3][4][4];
#pragma unroll
  for (int z = 0; z < 3; ++z)
#pragma unroll
    for (int i = 0; i < 4; ++i)
#pragma unroll
      for (int j = 0; j < 4; ++j) acc[z][i][j] = (f32x4){0.f, 0.f, 0.f, 0.f};

  const int khL = kgL >> 1;
  const int swz = (((kgL & 1) ^ ((lr >> 2) & 1)) << 4);
  const int aB0 = khL * (128 * 32) + (wm * 64 + lr) * 32 + swz;
  const int bB0 = khL * (128 * 32) + (wn * 64 + lr) * 32 + swz;

  const ushort_t* gA_h = Xh + (size_t)row0 * H_;
  const ushort_t* gA_l = Xl + (size_t)row0 * H_;
  const ushort_t* gB0 = WT4h + (size_t)col0 * H_;
  const ushort_t* gB1 = WT4h + (size_t)H_ * H_ + (size_t)col0 * H_;
  const ushort_t* gB2 = WT4h + (size_t)2 * H_ * H_ + (size_t)col0 * H_;

  auto stageall = [&](int k0, char* buf) {
    stage_slice<128>(gA_h + k0, H_, buf);
    stage_slice<128>(gA_l + k0, H_, buf + ABYTES);
    stage_slice<128>(gB0 + k0, H_, buf + 2 * ABYTES);
    stage_slice<128>(gB1 + k0, H_, buf + 3 * ABYTES);
    stage_slice<128>(gB2 + k0, H_, buf + 4 * ABYTES);
  };

  const int nk = H_ / 32;   // 24
  stageall(0, pool);
  for (int k = 0; k < nk; ++k) {
    char* cur = pool + (k & 1) * BUF;
    if (k + 1 < nk) {
      stageall((k + 1) * 32, pool + ((k + 1) & 1) * BUF);
      asm volatile("s_waitcnt vmcnt(10)" ::: "memory");
    } else {
      asm volatile("s_waitcnt vmcnt(0)" ::: "memory");
    }
    __builtin_amdgcn_s_barrier();
    asm volatile("" ::: "memory");

    bf16x8 a_h[4], a_l[4];
#pragma unroll
    for (int fm = 0; fm < 4; ++fm) {
      a_h[fm] = *(const bf16x8*)(cur + aB0 + fm * 512);
      a_l[fm] = *(const bf16x8*)(cur + ABYTES + aB0 + fm * 512);
    }
#pragma unroll
    for (int z = 0; z < 3; ++z) {
      const char* bP = cur + (2 + z) * ABYTES;
      bf16x8 b_h[4];
#pragma unroll
      for (int fn = 0; fn < 4; ++fn) b_h[fn] = *(const bf16x8*)(bP + bB0 + fn * 512);
#pragma unroll
      for (int fm = 0; fm < 4; ++fm)
#pragma unroll
        for (int fn = 0; fn < 4; ++fn) {
          f32x4 c = acc[z][fm][fn];
          c = __builtin_amdgcn_mfma_f32_16x16x32_bf16(a_h[fm], b_h[fn], c, 0, 0, 0);
          c = __builtin_amdgcn_mfma_f32_16x16x32_bf16(a_l[fm], b_h[fn], c, 0, 0, 0);
          acc[z][fm][fn] = c;
        }
    }
    asm volatile("" ::: "memory");
    __builtin_amdgcn_s_barrier();
  }

  const int kg = kgL;
#pragma unroll
  for (int fn = 0; fn < 4; ++fn) {
    const int col = col0 + wn * 64 + fn * 16 + lr;
    const float bvq = bq[col], bvk = bk[col], bvv2 = bvv[col];
#pragma unroll
    for (int fm = 0; fm < 4; ++fm) {
      const int rowb = row0 + wm * 64 + fm * 16 + kg * 4;
#pragma unroll
      for (int r = 0; r < 4; ++r) {
        float v = acc[0][fm][fn][r] + bvq;
        ushort_t h = f2bf(v);
        Qh[(size_t)(rowb + r) * H_ + col] = h;
        Ql[(size_t)(rowb + r) * H_ + col] = f2bf(v - bf2f(h));
      }
#pragma unroll
      for (int r = 0; r < 4; ++r) {
        Kh[(size_t)(rowb + r) * H_ + col] = f2bf(acc[1][fm][fn][r] + bvk);
      }
      {
        us4 h4;
#pragma unroll
        for (int r = 0; r < 4; ++r) h4[r] = f2bf(acc[2][fm][fn][r] + bvv2);
        const int bb2 = rowb >> 8, s0 = rowb & 255;
        const int hh2 = col >> 6, d = col & 63;
        *(us4*)(Vth + ((size_t)(bb2 * NH_ + hh2) * DH_ + d) * S_ + s0) = h4;
      }
    }
  }
}

// ---------------- MFMA flash attention, double-buffered K/V ----------------
__global__ __launch_bounds__(256, 3) void attn_mfma(
    const ushort_t* __restrict__ Qh, const ushort_t* __restrict__ Ql,
    const ushort_t* __restrict__ Kh, const ushort_t* __restrict__ Vth,
    const int* __restrict__ amask,
    ushort_t* __restrict__ Oh, ushort_t* __restrict__ Ol) {
  const int bid = blockIdx.x;
  const int qt = bid / 192;
  const int gh = bid - qt * 192;
  const int b = gh / NH_;
  const int h = gh - b * NH_;
  __shared__ __attribute__((aligned(16))) ushort_t sKh[2][64 * 64];
  __shared__ __attribute__((aligned(16))) ushort_t sVh[2][64 * 64];
  __shared__ __attribute__((aligned(16))) unsigned sP[4][16 * 68];
  __shared__ float sBias[2][64];
  const int tid = threadIdx.x;
  const int w = tid >> 6, lane = tid & 63;
  const int kg = lane >> 4, lr = lane & 15;

  const int qrow = b * S_ + qt * 64 + w * 16 + lr;
  bf16x8 qfh[2], qfl[2];
#pragma unroll
  for (int ds2 = 0; ds2 < 2; ++ds2) {
    const size_t off = (size_t)qrow * H_ + h * DH_ + ds2 * 32 + kg * 8;
    qfh[ds2] = *(const bf16x8*)(Qh + off);
    qfl[ds2] = *(const bf16x8*)(Ql + off);
  }

  f32x4 ctx[4];
#pragma unroll
  for (int i = 0; i < 4; ++i) ctx[i] = (f32x4){0.f, 0.f, 0.f, 0.f};
  float mrow[4], lrw[4];
#pragma unroll
  for (int r = 0; r < 4; ++r) { mrow[r] = -1e30f; lrw[r] = 0.f; }

  unsigned* sPw = &sP[w][0];

  auto stageKV = [&](int kt, int bufi) {
#pragma unroll
    for (int i = 0; i < 2; ++i) {
      const int v = tid + i * 256;
      const int row = v >> 3;
      const int c16 = (v & 7) ^ (row & 7);
      const size_t kgl = (size_t)(b * S_ + kt * 64 + row) * H_ + h * DH_ + c16 * 8;
      gload16(Kh + kgl, (char*)&sKh[bufi][0] + v * 16);
      const size_t vgl = (size_t)((b * NH_ + h) * DH_ + row) * S_ + kt * 64 + c16 * 8;
      gload16(Vth + vgl, (char*)&sVh[bufi][0] + v * 16);
    }
    if (tid < 64) sBias[bufi][tid] = (amask[b * S_ + kt * 64 + tid] > 0) ? 0.f : -1e9f;
  };

  stageKV(0, 0);
  for (int kt = 0; kt < 4; ++kt) {
    const int bi = kt & 1;
    if (kt < 3) {
      stageKV(kt + 1, bi ^ 1);
      asm volatile("s_waitcnt vmcnt(4) lgkmcnt(0)" ::: "memory");
    } else {
      asm volatile("s_waitcnt vmcnt(0) lgkmcnt(0)" ::: "memory");
    }
    __builtin_amdgcn_s_barrier();
    asm volatile("" ::: "memory");

    // QK^T
    f32x4 sc[4];
#pragma unroll
    for (int kf = 0; kf < 4; ++kf) sc[kf] = (f32x4){0.f, 0.f, 0.f, 0.f};
#pragma unroll
    for (int kf = 0; kf < 4; ++kf) {
      const int krow = kf * 16 + lr;
#pragma unroll
      for (int ds2 = 0; ds2 < 2; ++ds2) {
        const int cb = (ds2 * 64 + kg * 16) ^ ((krow & 7) << 4);
        const bf16x8 kvh = *(const bf16x8*)((const char*)&sKh[bi][0] + krow * 128 + cb);
        sc[kf] = __builtin_amdgcn_mfma_f32_16x16x32_bf16(qfh[ds2], kvh, sc[kf], 0, 0, 0);
        sc[kf] = __builtin_amdgcn_mfma_f32_16x16x32_bf16(qfl[ds2], kvh, sc[kf], 0, 0, 0);
      }
    }
    float bsv[4];
#pragma unroll
    for (int kf = 0; kf < 4; ++kf) bsv[kf] = sBias[bi][kf * 16 + lr];

#pragma unroll
    for (int r = 0; r < 4; ++r) {
      float sv[4];
      float tmax = -1e30f;
#pragma unroll
      for (int kf = 0; kf < 4; ++kf) {
        sv[kf] = sc[kf][r] * 0.125f + bsv[kf];
        tmax = fmaxf(tmax, sv[kf]);
      }
#pragma unroll
      for (int o = 8; o > 0; o >>= 1) tmax = fmaxf(tmax, __shfl_xor(tmax, o, 64));
      const float mnew = fmaxf(mrow[r], tmax);
      const float corr = expf(mrow[r] - mnew);
      float ls = 0.f;
      const int qoff = (kg * 4 + r) * 68;
#pragma unroll
      for (int kf = 0; kf < 4; ++kf) {
        const float pe = expf(sv[kf] - mnew);
        ls += pe;
        const ushort_t hi = f2bf(pe);
        const ushort_t lo = f2bf(pe - bf2f(hi));
        sPw[qoff + kf * 16 + lr] = ((unsigned)hi << 16) | lo;
      }
#pragma unroll
      for (int o = 8; o > 0; o >>= 1) ls += __shfl_xor(ls, o, 64);
      lrw[r] = lrw[r] * corr + ls;
      mrow[r] = mnew;
#pragma unroll
      for (int df = 0; df < 4; ++df) ctx[df][r] *= corr;
    }

    // PV
#pragma unroll
    for (int ks = 0; ks < 2; ++ks) {
      unsigned w8[8];
      *(u32x4*)&w8[0] = *(const u32x4*)(sPw + lr * 68 + ks * 32 + kg * 8);
      *(u32x4*)&w8[4] = *(const u32x4*)(sPw + lr * 68 + ks * 32 + kg * 8 + 4);
      union { bf16x8 v; ushort_t u[8]; } ph, pl;
#pragma unroll
      for (int j = 0; j < 8; ++j) { ph.u[j] = (ushort_t)(w8[j] >> 16); pl.u[j] = (ushort_t)(w8[j] & 0xffffu); }
#pragma unroll
      for (int df = 0; df < 4; ++df) {
        const int vrow = df * 16 + lr;
        const int cb = (ks * 64 + kg * 16) ^ ((vrow & 7) << 4);
        const bf16x8 vvh = *(const bf16x8*)((const char*)&sVh[bi][0] + vrow * 128 + cb);
        ctx[df] = __builtin_amdgcn_mfma_f32_16x16x32_bf16(ph.v, vvh, ctx[df], 0, 0, 0);
        ctx[df] = __builtin_amdgcn_mfma_f32_16x16x32_bf16(pl.v, vvh, ctx[df], 0, 0, 0);
      }
    }
    asm volatile("" ::: "memory");
    __builtin_amdgcn_s_barrier();
  }

#pragma unroll
  for (int r = 0; r < 4; ++r) {
    const float inv = 1.f / lrw[r];
    const int tok = b * S_ + qt * 64 + w * 16 + kg * 4 + r;
#pragma unroll
    for (int df = 0; df < 4; ++df) {
      const float v = ctx[df][r] * inv;
      const ushort_t hi = f2bf(v);
      const size_t o = (size_t)tok * H_ + h * DH_ + df * 16 + lr;
      Oh[o] = hi;
      Ol[o] = f2bf(v - bf2f(hi));
    }
  }
}

// ---------------- CRF v5: readlane broadcast, zero-LDS recurrence ----------------
__global__ __launch_bounds__(128) void crf_kernel(const float* __restrict__ emis, const int* __restrict__ tags,
                          const int* __restrict__ amask,
                          const float* __restrict__ crf_start, const float* __restrict__ crf_end,
                          const float* __restrict__ trans,
                          float* __restrict__ partial, float* __restrict__ out) {
  const int b = blockIdx.x;
  const int tid = threadIdx.x;
  const int wv = tid >> 6;
  const int lane = tid & 63;
  __shared__ float sE[S_ * T_];
  __shared__ float sM[S_];
  __shared__ float trs[T_ * T_];
  __shared__ unsigned char hist[S_ - 1][16];
  __shared__ float pathf[S_];
  for (int i = tid; i < S_ * T_; i += 128) {
    const int s = i / T_, t = i - s * T_;
    sE[i] = emis[((size_t)s * B_ + b) * T_ + t];
  }
  for (int i = tid; i < S_; i += 128) sM[i] = (float)amask[b * S_ + i];
  for (int i = tid; i < T_ * T_; i += 128) trs[i] = trans[i];
  __syncthreads();

  const int t = lane;
  const bool act = t < T_;
  float trc[T_];
#pragma unroll
  for (int p = 0; p < T_; ++p) trc[p] = act ? trs[p * T_ + t] : 0.f;

  if (wv == 0) {
    float alpha = act ? crf_start[t] + sE[t] : 0.f;
    for (int s = 1; s < S_; ++s) {
      float ap[T_];
#pragma unroll
      for (int p = 0; p < T_; ++p) ap[p] = rdlane(alpha, p);
      if (act) {
        const float e = sE[s * T_ + t];
        float v[T_];
#pragma unroll
        for (int p = 0; p < T_; ++p) v[p] = ap[p] + trc[p];
        float m0 = fmaxf(fmaxf(v[0], v[1]), fmaxf(v[2], v[3]));
        float m1 = fmaxf(fmaxf(v[4], v[5]), fmaxf(v[6], v[7]));
        const float mx = fmaxf(fmaxf(m0, m1), v[8]);
        float sum = 0.f;
#pragma unroll
        for (int p = 0; p < T_; ++p) sum += __expf(v[p] - mx);
        const float na = mx + __logf(sum) + e;
        if (sM[s] > 0.f) alpha = na;
      }
    }
    float nsum = 0.f;
    int len = 0;
#pragma unroll
    for (int j = 0; j < 4; ++j) {
      const int s = lane + j * 64;
      const int mk = (sM[s] > 0.f) ? 1 : 0;
      len += mk;
      if (s >= 1 && mk) {
        const int tc = tags[b * S_ + s], tp = tags[b * S_ + s - 1];
        nsum += trs[tp * T_ + tc] + sE[s * T_ + tc];
      }
    }
#pragma unroll
    for (int o = 32; o > 0; o >>= 1) {
      nsum += __shfl_xor(nsum, o, 64);
      len += __shfl_xor(len, o, 64);
    }
    const float fz = act ? alpha + crf_end[t] : -1e30f;
    float zp[T_];
#pragma unroll
    for (int p = 0; p < T_; ++p) zp[p] = rdlane(fz, p);
    if (lane == 0) {
      float mx = -1e30f;
#pragma unroll
      for (int p = 0; p < T_; ++p) mx = fmaxf(mx, zp[p]);
      float sum = 0.f;
#pragma unroll
      for (int p = 0; p < T_; ++p) sum += __expf(zp[p] - mx);
      const float logZ = mx + __logf(sum);
      const int tg0 = tags[b * S_];
      const float score = nsum + crf_start[tg0] + sE[tg0] + crf_end[tags[b * S_ + len - 1]];
      partial[b] = score - logZ;
    }
  } else {
    float vit = act ? crf_start[t] + sE[t] : 0.f;
    for (int s = 1; s < S_; ++s) {
      float vp[T_];
#pragma unroll
      for (int p = 0; p < T_; ++p) vp[p] = rdlane(vit, p);
      if (act) {
        const float e = sE[s * T_ + t];
        float best = -1e30f; int bi = 0;
#pragma unroll
        for (int p = 0; p < T_; ++p) {
          const float scv = vp[p] + trc[p];
          if (scv > best) { best = scv; bi = p; }
        }
        if (sM[s] > 0.f) {
          vit = best + e;
          hist[s - 1][t] = (unsigned char)bi;
        } else {
          hist[s - 1][t] = (unsigned char)t;
        }
      }
    }
    const float fv = act ? vit + crf_end[t] : -1e30f;
    float wp[T_];
#pragma unroll
    for (int p = 0; p < T_; ++p) wp[p] = rdlane(fv, p);
    if (lane == 0) {
      float best = -1e30f; int lastTag = 0;
#pragma unroll
      for (int p = 0; p < T_; ++p) {
        if (wp[p] > best) { best = wp[p]; lastTag = p; }
      }
      int tc = lastTag;
      pathf[S_ - 1] = (float)tc;
      for (int i = S_ - 2; i >= 0; --i) {
        tc = hist[i][tc];
        pathf[i] = (float)tc;
      }
    }
  }
  __syncthreads();
#pragma unroll
  for (int j = 0; j < 2; ++j) {
    const int s = tid + j * 128;
    out[1 + b * S_ + s] = pathf[s];
  }
}

__global__ __launch_bounds__(64) void crf_final(const float* __restrict__ partial, float* __restrict__ out) {
  const int lane = threadIdx.x;
  float v = (lane < B_) ? partial[lane] : 0.f;
#pragma unroll
  for (int o = 32; o > 0; o >>= 1) v += __shfl_xor(v, o, 64);
  if (lane == 0) out[0] = -(v * (1.f / B_));
}

extern "C" void kernel_launch(void* const* d_in, const int* in_sizes, int n_in,
                              void* d_out, int out_size, void* d_ws, size_t ws_size,
                              hipStream_t stream) {
  const int* input_ids = (const int*)d_in[0];
  const int* token_type_ids = (const int*)d_in[1];
  const int* attention_mask = (const int*)d_in[2];
  const int* tags = (const int*)d_in[3];
  const float* word_emb = (const float*)d_in[4];
  const float* pos_emb = (const float*)d_in[5];
  const float* type_emb = (const float*)d_in[6];
  const float* emb_ln_g = (const float*)d_in[7];
  const float* emb_ln_b = (const float*)d_in[8];
  const float* Wq = (const float*)d_in[9];
  const float* bq = (const float*)d_in[10];
  const float* Wk = (const float*)d_in[11];
  const float* bk = (const float*)d_in[12];
  const float* Wv = (const float*)d_in[13];
  const float* bv = (const float*)d_in[14];
  const float* Wo = (const float*)d_in[15];
  const float* bo = (const float*)d_in[16];
  const float* ln1_g = (const float*)d_in[17];
  const float* ln1_b = (const float*)d_in[18];
  const float* W1 = (const float*)d_in[19];
  const float* b1 = (const float*)d_in[20];
  const float* W2 = (const float*)d_in[21];
  const float* b2 = (const float*)d_in[22];
  const float* ln2_g = (const float*)d_in[23];
  const float* ln2_b = (const float*)d_in[24];
  const float* dense_W = (const float*)d_in[25];
  const float* dense_b = (const float*)d_in[26];
  const float* crf_start = (const float*)d_in[27];
  const float* crf_end = (const float*)d_in[28];
  const float* crf_trans = (const float*)d_in[29];

  constexpr size_t NTOK = (size_t)B_ * S_;        // 4096
  constexpr size_t XSZ = NTOK * H_;               // 3,145,728
  constexpr size_t WT4SZ = (size_t)4 * H_ * H_;   // 2,359,296
  constexpr size_t WFSZ = (size_t)H_ * FF_;       // 2,359,296

  char* p = (char*)d_ws;
  float* TMP = (float*)p;          p += XSZ * 4;
  char* UN = p;                    p += 8 * XSZ * 2;     // 50.33 MB union
  ushort_t* Qh = (ushort_t*)UN;
  ushort_t* Ql = Qh + XSZ;
  ushort_t* Kh = Ql + XSZ;
  ushort_t* Vth = Kh + XSZ;
  ushort_t* CTXh = Vth + XSZ;
  ushort_t* CTXl = CTXh + XSZ;
  ushort_t* FFh = (ushort_t*)UN;                        // aliases QKV after dead
  ushort_t* FFl = FFh + NTOK * FF_;
  ushort_t* Xh = (ushort_t*)p;     p += XSZ * 2;
  ushort_t* Xl = (ushort_t*)p;     p += XSZ * 2;
  ushort_t* WT4h2 = (ushort_t*)p;  p += WT4SZ * 2 * 2;  // double-buffered
  ushort_t* W1th2 = (ushort_t*)p;  p += WFSZ * 2 * 2;
  ushort_t* W2th2 = (ushort_t*)p;  p += WFSZ * 2 * 2;
  float* EM = (float*)p;           p += (size_t)S_ * B_ * T_ * 4;
  float* PART = (float*)p;         p += B_ * 4;

  emb_ln_kernel<<<dim3(4096), dim3(256), 0, stream>>>(input_ids, token_type_ids, word_emb, pos_emb,
                                                      type_emb, emb_ln_g, emb_ln_b, Xh, Xl);
  // layer 0 weights into parity 0
  wprep_k<<<dim3(1728), dim3(256), 0, stream>>>(Wq, Wk, Wv, Wo, W1, W2, WT4h2, W1th2, W2th2);

  for (int l = 0; l < L_; ++l) {
    const int pr = l & 1, pn = (l + 1) & 1;
    ushort_t* WT4h = WT4h2 + (size_t)pr * WT4SZ;
    ushort_t* W1th = W1th2 + (size_t)pr * WFSZ;
    ushort_t* W2th = W2th2 + (size_t)pr * WFSZ;
    const bool hasNext = (l + 1 < L_);
    const size_t wo_n = (size_t)(l + 1) * H_ * H_;

    qkv_m<<<dim3(6, 32), dim3(256), 0, stream>>>(Xh, Xl, WT4h, bq + (size_t)l * H_,
                                                 bk + (size_t)l * H_, bv + (size_t)l * H_,
                                                 Qh, Ql, Kh, Vth);
    attn_mfma<<<dim3(768), dim3(256), 0, stream>>>(Qh, Ql, Kh, Vth, attention_mask, CTXh, CTXl);
    mgemm<128, 128, 32, 0><<<dim3(6, 32), dim3(256), 0, stream>>>(
        CTXh, CTXl, WT4h + (size_t)3 * H_ * H_,
        bo + (size_t)l * H_, TMP, nullptr, nullptr, H_, H_);
    ln_kernel<<<dim3(4096), dim3(256), 0, stream>>>(Xh, Xl, TMP, ln1_g + (size_t)l * H_,
                                                    ln1_b + (size_t)l * H_, Xh, Xl);
    ff1_fused<<<dim3(12, 32 + 144), dim3(256), 0, stream>>>(
        Xh, Xl, W1th, b1 + (size_t)l * FF_, FFh, FFl,
        hasNext ? Wq + wo_n : nullptr, Wk + wo_n, Wv + wo_n, Wo + wo_n,
        W1 + (size_t)(l + 1) * WFSZ, W2 + (size_t)(l + 1) * WFSZ,
        WT4h2 + (size_t)pn * WT4SZ, W1th2 + (size_t)pn * WFSZ, W2th2 + (size_t)pn * WFSZ);
    mgemm<128, 128, 32, 0><<<dim3(6, 32), dim3(256), 0, stream>>>(
        FFh, FFl, W2th, b2 + (size_t)l * H_, TMP, nullptr, nullptr, H_, FF_);
    if (l + 1 < L_) {
      ln_kernel<<<dim3(4096), dim3(256), 0, stream>>>(Xh, Xl, TMP, ln2_g + (size_t)l * H_,
                                                      ln2_b + (size_t)l * H_, Xh, Xl);
    } else {
      ln_emis_kernel<<<dim3(4096), dim3(256), 0, stream>>>(Xh, Xl, TMP, ln2_g + (size_t)l * H_,
                                                           ln2_b + (size_t)l * H_, dense_W,
                                                           dense_b, EM);
    }
  }

  crf_kernel<<<dim3(B_), dim3(128), 0, stream>>>(EM, tags, attention_mask, crf_start, crf_end,
                                                 crf_trans, PART, (float*)d_out);
  crf_final<<<dim3(1), dim3(64), 0, stream>>>(PART, (float*)d_out);
}

// Round 15
// 3063.670 us; speedup vs baseline: 1.0327x; 1.0152x over previous
//
#include <hip/hip_runtime.h>
#include <math.h>

#define B_ 16
#define S_ 256
#define H_ 768
#define L_ 12
#define NH_ 12
#define DH_ 64
#define FF_ 3072
#define T_ 9

typedef unsigned short ushort_t;
typedef __attribute__((ext_vector_type(8))) __bf16 bf16x8;
typedef __attribute__((ext_vector_type(4))) float f32x4;
typedef __attribute__((ext_vector_type(4))) unsigned short us4;
typedef __attribute__((ext_vector_type(8))) unsigned short us8;
typedef __attribute__((ext_vector_type(4))) unsigned int u32x4;

__device__ __forceinline__ ushort_t f2bf(float f) {
  union { float f; unsigned u; } v; v.f = f;
  unsigned r = v.u + 0x7FFFu + ((v.u >> 16) & 1u);
  return (ushort_t)(r >> 16);
}
__device__ __forceinline__ float bf2f(ushort_t h) {
  union { unsigned u; float f; } v; v.u = ((unsigned)h) << 16;
  return v.f;
}
__device__ __forceinline__ float rdlane(float v, int l) {
  union { float f; int i; } u; u.f = v;
  union { int i; float f; } o; o.i = __builtin_amdgcn_readlane(u.i, l);
  return o.f;
}
__device__ __forceinline__ void gload16(const void* g, void* l) {
  __builtin_amdgcn_global_load_lds((const __attribute__((address_space(1))) void*)g,
                                   (__attribute__((address_space(3))) void*)l, 16, 0, 0);
}

// ---------------- fused embedding sum + layernorm (hi/lo out only) ----------------
__global__ __launch_bounds__(256) void emb_ln_kernel(const int* __restrict__ ids, const int* __restrict__ tt,
                              const float* __restrict__ we, const float* __restrict__ pe,
                              const float* __restrict__ te, const float* __restrict__ g,
                              const float* __restrict__ bb,
                              ushort_t* __restrict__ oh, ushort_t* __restrict__ ol) {
  const int token = blockIdx.x;
  const int tid = threadIdx.x;
  const int s = token & (S_ - 1);
  const int id = ids[token];
  const int t2 = tt[token];
  float x[3];
  float sum = 0.f;
#pragma unroll
  for (int i = 0; i < 3; ++i) {
    int d = tid + i * 256;
    x[i] = we[(size_t)id * H_ + d] + pe[(size_t)s * H_ + d] + te[(size_t)t2 * H_ + d];
    sum += x[i];
  }
  __shared__ float red[4];
#pragma unroll
  for (int o = 32; o > 0; o >>= 1) sum += __shfl_xor(sum, o, 64);
  const int wid = tid >> 6, lane = tid & 63;
  if (lane == 0) red[wid] = sum;
  __syncthreads();
  const float mean = (red[0] + red[1] + red[2] + red[3]) * (1.f / H_);
  float vs = 0.f;
#pragma unroll
  for (int i = 0; i < 3; ++i) { float dv = x[i] - mean; vs += dv * dv; }
#pragma unroll
  for (int o = 32; o > 0; o >>= 1) vs += __shfl_xor(vs, o, 64);
  __syncthreads();
  if (lane == 0) red[wid] = vs;
  __syncthreads();
  const float var = (red[0] + red[1] + red[2] + red[3]) * (1.f / H_);
  const float inv = rsqrtf(var + 1e-12f);
  ushort_t* hp = oh + (size_t)token * H_;
  ushort_t* lp = ol + (size_t)token * H_;
#pragma unroll
  for (int i = 0; i < 3; ++i) {
    int d = tid + i * 256;
    float y = (x[i] - mean) * inv * g[d] + bb[d];
    ushort_t h = f2bf(y);
    hp[d] = h;
    lp[d] = f2bf(y - bf2f(h));
  }
}

// ---------------- layernorm: base from hi/lo pair + f32 delta -> hi/lo out ----------------
__global__ __launch_bounds__(256) void ln_kernel(const ushort_t* __restrict__ bh, const ushort_t* __restrict__ bl,
                          const float* __restrict__ delta,
                          const float* __restrict__ g, const float* __restrict__ bb,
                          ushort_t* __restrict__ oh, ushort_t* __restrict__ ol) {
  const int token = blockIdx.x;
  const int tid = threadIdx.x;
  const ushort_t* bhp = bh + (size_t)token * H_;
  const ushort_t* blp = bl + (size_t)token * H_;
  const float* dp = delta + (size_t)token * H_;
  float x[3];
  float s = 0.f;
#pragma unroll
  for (int i = 0; i < 3; ++i) {
    int d = tid + i * 256;
    x[i] = bf2f(bhp[d]) + bf2f(blp[d]) + dp[d];
    s += x[i];
  }
  __shared__ float red[4];
#pragma unroll
  for (int o = 32; o > 0; o >>= 1) s += __shfl_xor(s, o, 64);
  const int wid = tid >> 6, lane = tid & 63;
  if (lane == 0) red[wid] = s;
  __syncthreads();
  const float mean = (red[0] + red[1] + red[2] + red[3]) * (1.f / H_);
  float vs = 0.f;
#pragma unroll
  for (int i = 0; i < 3; ++i) { float dv = x[i] - mean; vs += dv * dv; }
#pragma unroll
  for (int o = 32; o > 0; o >>= 1) vs += __shfl_xor(vs, o, 64);
  __syncthreads();
  if (lane == 0) red[wid] = vs;
  __syncthreads();
  const float var = (red[0] + red[1] + red[2] + red[3]) * (1.f / H_);
  const float inv = rsqrtf(var + 1e-12f);
  ushort_t* hp = oh + (size_t)token * H_;
  ushort_t* lp = ol + (size_t)token * H_;
#pragma unroll
  for (int i = 0; i < 3; ++i) {
    int d = tid + i * 256;
    float y = (x[i] - mean) * inv * g[d] + bb[d];
    ushort_t h = f2bf(y);
    hp[d] = h;
    lp[d] = f2bf(y - bf2f(h));
  }
}

// ---------------- final layernorm + emissions fused ----------------
__global__ __launch_bounds__(256) void ln_emis_kernel(const ushort_t* __restrict__ bh, const ushort_t* __restrict__ bl,
                               const float* __restrict__ delta,
                               const float* __restrict__ g, const float* __restrict__ bb,
                               const float* __restrict__ W, const float* __restrict__ wbias,
                               float* __restrict__ E) {
  const int token = blockIdx.x;
  const int tid = threadIdx.x;
  __shared__ float sW[H_ * T_];     // 27 KB
  __shared__ float red[4];
  __shared__ float wred[4][12];
  for (int i = tid; i < H_ * T_; i += 256) sW[i] = W[i];

  const ushort_t* bhp = bh + (size_t)token * H_;
  const ushort_t* blp = bl + (size_t)token * H_;
  const float* dp = delta + (size_t)token * H_;
  float x[3];
  float s = 0.f;
#pragma unroll
  for (int i = 0; i < 3; ++i) {
    int d = tid + i * 256;
    x[i] = bf2f(bhp[d]) + bf2f(blp[d]) + dp[d];
    s += x[i];
  }
#pragma unroll
  for (int o = 32; o > 0; o >>= 1) s += __shfl_xor(s, o, 64);
  const int wid = tid >> 6, lane = tid & 63;
  if (lane == 0) red[wid] = s;
  __syncthreads();
  const float mean = (red[0] + red[1] + red[2] + red[3]) * (1.f / H_);
  float vs = 0.f;
#pragma unroll
  for (int i = 0; i < 3; ++i) { float dv = x[i] - mean; vs += dv * dv; }
#pragma unroll
  for (int o = 32; o > 0; o >>= 1) vs += __shfl_xor(vs, o, 64);
  __syncthreads();
  if (lane == 0) red[wid] = vs;
  __syncthreads();
  const float var = (red[0] + red[1] + red[2] + red[3]) * (1.f / H_);
  const float inv = rsqrtf(var + 1e-12f);

  float acc9[T_];
#pragma unroll
  for (int t = 0; t < T_; ++t) acc9[t] = 0.f;
#pragma unroll
  for (int i = 0; i < 3; ++i) {
    int d = tid + i * 256;
    float y = (x[i] - mean) * inv * g[d] + bb[d];
    const float* wr = sW + d * T_;
#pragma unroll
    for (int t = 0; t < T_; ++t) acc9[t] = fmaf(y, wr[t], acc9[t]);
  }
#pragma unroll
  for (int o = 32; o > 0; o >>= 1)
#pragma unroll
    for (int t = 0; t < T_; ++t) acc9[t] += __shfl_xor(acc9[t], o, 64);
  if (lane == 0) {
#pragma unroll
    for (int t = 0; t < T_; ++t) wred[wid][t] = acc9[t];
  }
  __syncthreads();
  if (tid < T_) {
    const float v = wred[0][tid] + wred[1][tid] + wred[2][tid] + wred[3][tid] + wbias[tid];
    const int b2 = token >> 8, s2 = token & 255;
    E[((size_t)s2 * B_ + b2) * T_ + tid] = v;
  }
}

// ---------------- weight transpose + bf16 round: src[K][N] f32 -> dst[N][K] ----------------
__device__ __forceinline__ void transpose_core(float (*t)[65], const float* __restrict__ src,
                                               ushort_t* __restrict__ dh,
                                               int K, int N, int n0, int k0) {
  const int tid = threadIdx.x;
#pragma unroll
  for (int i = 0; i < 16; ++i) {
    int lin = tid + i * 256;
    int kk = lin >> 6, nn = lin & 63;
    t[kk][nn] = src[(size_t)(k0 + kk) * N + n0 + nn];
  }
  __syncthreads();
#pragma unroll
  for (int i = 0; i < 16; ++i) {
    int lin = tid + i * 256;
    int nn = lin >> 6, kk = lin & 63;
    dh[(size_t)(n0 + nn) * K + k0 + kk] = f2bf(t[kk][nn]);
  }
}

__device__ __forceinline__ void wprep_dispatch(float (*t)[65], int wid,
                        const float* Wq, const float* Wk, const float* Wv, const float* Wo,
                        const float* W1, const float* W2,
                        ushort_t* WT4h, ushort_t* W1th, ushort_t* W2th) {
  if (wid < 576) {
    const int z = wid / 144, r = wid - z * 144;
    const int x = r % 12, y = r / 12;
    const float* src = z == 0 ? Wq : (z == 1 ? Wk : (z == 2 ? Wv : Wo));
    transpose_core(t, src, WT4h + (size_t)z * H_ * H_, H_, H_, x * 64, y * 64);
  } else if (wid < 1152) {
    const int i = wid - 576;
    const int x = i % 48, y = i / 48;
    transpose_core(t, W1, W1th, H_, FF_, x * 64, y * 64);
  } else {
    const int i = wid - 1152;
    const int x = i % 12, y = i / 12;
    transpose_core(t, W2, W2th, FF_, H_, x * 64, y * 64);
  }
}

__global__ __launch_bounds__(256) void wprep_k(const float* __restrict__ Wq, const float* __restrict__ Wk,
                        const float* __restrict__ Wv, const float* __restrict__ Wo,
                        const float* __restrict__ W1, const float* __restrict__ W2,
                        ushort_t* __restrict__ WT4h,
                        ushort_t* __restrict__ W1th, ushort_t* __restrict__ W2th) {
  __shared__ float t[64][65];
  wprep_dispatch(t, blockIdx.x, Wq, Wk, Wv, Wo, W1, W2, WT4h, W1th, W2th);
}

// ---------------- conflict-free staging (proven mapping), one 32-K slice ----------------
template <int R>
__device__ __forceinline__ void stage_slice(const ushort_t* __restrict__ gsrc, int K, char* lds) {
  const int tid = threadIdx.x;
  constexpr int NIT = (R * 4) / 256;
#pragma unroll
  for (int i = 0; i < NIT; ++i) {
    const int v = tid + i * 256;
    const int kh = v / (2 * R);
    const int r2 = v & (2 * R - 1);
    const int row = r2 >> 1;
    const int kg = (kh << 1) | ((r2 & 1) ^ ((row >> 2) & 1));
    gload16(gsrc + (size_t)row * K + kg * 8, lds + (i * 256 + (tid & 192)) * 16);
  }
}

// ---------------- split-A MFMA GEMM core, double-buffered: acc = (Ah+Al) * Bh^T ----------------
template <int BM, int BN, int BK>
__device__ __forceinline__ void mgemm_acc(
    const ushort_t* __restrict__ Ah, const ushort_t* __restrict__ Al,
    const ushort_t* __restrict__ Bth,
    int K, f32x4 (&acc)[BM / 32][BN / 32], char* pool) {
  constexpr int FM = BM / 32;
  constexpr int FN = BN / 32;
  constexpr int ABYTES = BM * BK * 2;
  constexpr int BBYTES = BN * BK * 2;
  constexpr int BUF = 2 * ABYTES + BBYTES;
  constexpr int NL = (8 * BM + 4 * BN) / 256;
  const int tid = threadIdx.x;
  const int w = tid >> 6, lane = tid & 63;
  const int wm = w >> 1, wn = w & 1;
  const int kgL = lane >> 4, lr = lane & 15;
  const int row0 = blockIdx.y * BM, col0 = blockIdx.x * BN;

#pragma unroll
  for (int i = 0; i < FM; ++i)
#pragma unroll
    for (int j = 0; j < FN; ++j) acc[i][j] = (f32x4){0.f, 0.f, 0.f, 0.f};

  const int khL = kgL >> 1;
  const int swz = (((kgL & 1) ^ ((lr >> 2) & 1)) << 4);
  const int aB0 = khL * (BM * 32) + (wm * (BM / 2) + lr) * 32 + swz;
  const int bB0 = khL * (BN * 32) + (wn * (BN / 2) + lr) * 32 + swz;

  const ushort_t* gA_h = Ah + (size_t)row0 * K;
  const ushort_t* gA_l = Al + (size_t)row0 * K;
  const ushort_t* gB_h = Bth + (size_t)col0 * K;

  auto stageall = [&](int k0, char* buf) {
#pragma unroll
    for (int c = 0; c < BK / 32; ++c) {
      stage_slice<BM>(gA_h + k0 + c * 32, K, buf + c * BM * 64);
      stage_slice<BM>(gA_l + k0 + c * 32, K, buf + ABYTES + c * BM * 64);
      stage_slice<BN>(gB_h + k0 + c * 32, K, buf + 2 * ABYTES + c * BN * 64);
    }
  };

  const int nk = K / BK;
  stageall(0, pool);
  for (int k = 0; k < nk; ++k) {
    char* cur = pool + (k & 1) * BUF;
    if (k + 1 < nk) {
      stageall((k + 1) * BK, pool + ((k + 1) & 1) * BUF);
      if constexpr (NL == 6) {
        asm volatile("s_waitcnt vmcnt(6)" ::: "memory");
      } else if constexpr (NL == 8) {
        asm volatile("s_waitcnt vmcnt(8)" ::: "memory");
      } else {
        asm volatile("s_waitcnt vmcnt(0)" ::: "memory");
      }
    } else {
      asm volatile("s_waitcnt vmcnt(0)" ::: "memory");
    }
    __builtin_amdgcn_s_barrier();
    asm volatile("" ::: "memory");

#pragma unroll
    for (int ks = 0; ks < BK / 32; ++ks) {
      const char* aP = cur + ks * BM * 64;
      const char* bP = cur + 2 * ABYTES + ks * BN * 64;
      bf16x8 a_h[FM], a_l[FM], b_h[FN];
#pragma unroll
      for (int fm = 0; fm < FM; ++fm) {
        a_h[fm] = *(const bf16x8*)(aP + aB0 + fm * 512);
        a_l[fm] = *(const bf16x8*)(aP + ABYTES + aB0 + fm * 512);
      }
#pragma unroll
      for (int fn = 0; fn < FN; ++fn) {
        b_h[fn] = *(const bf16x8*)(bP + bB0 + fn * 512);
      }
#pragma unroll
      for (int fm = 0; fm < FM; ++fm)
#pragma unroll
        for (int fn = 0; fn < FN; ++fn) {
          f32x4 c = acc[fm][fn];
          c = __builtin_amdgcn_mfma_f32_16x16x32_bf16(a_h[fm], b_h[fn], c, 0, 0, 0);
          c = __builtin_amdgcn_mfma_f32_16x16x32_bf16(a_l[fm], b_h[fn], c, 0, 0, 0);
          acc[fm][fn] = c;
        }
    }
    asm volatile("" ::: "memory");
    __builtin_amdgcn_s_barrier();
  }
}

// generic GEMM, f32 out with coalesced LDS-transpose epilogue
template <int BM, int BN, int BK, int EPI>
__global__ __launch_bounds__(256, 3) void mgemm(const ushort_t* __restrict__ Ah, const ushort_t* __restrict__ Al,
                      const ushort_t* __restrict__ Bth,
                      const float* __restrict__ bias, float* __restrict__ Cf,
                      ushort_t* __restrict__ Ch, ushort_t* __restrict__ Cl, int N, int K) {
  __shared__ __attribute__((aligned(16))) char pool[2 * (2 * BM * BK + BN * BK) * 2];
  f32x4 acc[BM / 32][BN / 32];
  mgemm_acc<BM, BN, BK>(Ah, Al, Bth, K, acc, pool);
  const int tid = threadIdx.x;
  const int w = tid >> 6, lane = tid & 63;
  const int wm = w >> 1, wn = w & 1;
  const int kg = lane >> 4, lr = lane & 15;
  const int row0 = blockIdx.y * BM, col0 = blockIdx.x * BN;
  float* tb = (float*)pool + w * (16 * 68);
  const int row0w = row0 + wm * (BM / 2);
  const int col0w = col0 + wn * (BN / 2);
#pragma unroll
  for (int fm = 0; fm < BM / 32; ++fm) {
#pragma unroll
    for (int fn = 0; fn < BN / 32; ++fn) {
      const int col = col0w + fn * 16 + lr;
      const float bv = bias[col];
#pragma unroll
      for (int r = 0; r < 4; ++r)
        tb[(kg * 4 + r) * 68 + fn * 16 + lr] = acc[fm][fn][r] + bv;
    }
#pragma unroll
    for (int it = 0; it < (BN / 16) / 8; ++it) {   // (16 rows * BN/16 groups) / 64 lanes
      const int slot = it * 64 + lane;
      const int row16 = slot / (BN / 16);
      const int cg = slot % (BN / 16);
      const f32x4 a = *(const f32x4*)&tb[row16 * 68 + cg * 8];
      const f32x4 b2 = *(const f32x4*)&tb[row16 * 68 + cg * 8 + 4];
      const int grow = row0w + fm * 16 + row16;
      const size_t o = (size_t)grow * N + col0w + cg * 8;
      *(f32x4*)(Cf + o) = a;
      *(f32x4*)(Cf + o + 4) = b2;
    }
  }
}

// FF1 (GELU epilogue, BN=256, coalesced) + folded weight-prep (blockIdx.y >= 32)
__global__ __launch_bounds__(256, 2) void ff1_fused(
    const ushort_t* __restrict__ Xh, const ushort_t* __restrict__ Xl,
    const ushort_t* __restrict__ W1th, const float* __restrict__ bias,
    ushort_t* __restrict__ Ch, ushort_t* __restrict__ Cl,
    const float* __restrict__ WqN, const float* __restrict__ WkN,
    const float* __restrict__ WvN, const float* __restrict__ WoN,
    const float* __restrict__ W1N, const float* __restrict__ W2N,
    ushort_t* __restrict__ WT4hN, ushort_t* __restrict__ W1thN, ushort_t* __restrict__ W2thN) {
  __shared__ __attribute__((aligned(16))) char pool[2 * (2 * 128 * 32 + 256 * 32) * 2];  // 64 KB
  if (blockIdx.y >= 32) {
    if (WqN == nullptr) return;
    const int wid = (blockIdx.y - 32) * 12 + blockIdx.x;
    wprep_dispatch((float(*)[65])pool, wid, WqN, WkN, WvN, WoN, W1N, W2N, WT4hN, W1thN, W2thN);
    return;
  }
  f32x4 acc[4][8];
  mgemm_acc<128, 256, 32>(Xh, Xl, W1th, H_, acc, pool);
  const int tid = threadIdx.x;
  const int w = tid >> 6, lane = tid & 63;
  const int wm = w >> 1, wn = w & 1;
  const int kg = lane >> 4, lr = lane & 15;
  const int row0 = blockIdx.y * 128, col0 = blockIdx.x * 256;
  unsigned* tb = (unsigned*)pool + w * (16 * 132);
  const int row0w = row0 + wm * 64;
  const int col0w = col0 + wn * 128;
#pragma unroll
  for (int fm = 0; fm < 4; ++fm) {
#pragma unroll
    for (int fn = 0; fn < 8; ++fn) {
      const int col = col0w + fn * 16 + lr;
      const float bv = bias[col];
#pragma unroll
      for (int r = 0; r < 4; ++r) {
        float v = acc[fm][fn][r] + bv;
        float gl = 0.5f * v * (1.f + erff(v * 0.70710678118654752f));
        ushort_t h = f2bf(gl);
        ushort_t lo = f2bf(gl - bf2f(h));
        tb[(kg * 4 + r) * 132 + fn * 16 + lr] = ((unsigned)h << 16) | lo;
      }
    }
#pragma unroll
    for (int it = 0; it < 4; ++it) {
      const int slot = it * 64 + lane;
      const int row16 = slot >> 4, cg = slot & 15;
      unsigned r8[8];
      *(u32x4*)&r8[0] = *(const u32x4*)&tb[row16 * 132 + cg * 8];
      *(u32x4*)&r8[4] = *(const u32x4*)&tb[row16 * 132 + cg * 8 + 4];
      us8 h8, l8;
#pragma unroll
      for (int j = 0; j < 8; ++j) {
        h8[j] = (ushort_t)(r8[j] >> 16);
        l8[j] = (ushort_t)(r8[j] & 0xffffu);
      }
      const int grow = row0w + fm * 16 + row16;
      const size_t o = (size_t)grow * FF_ + col0w + cg * 8;
      *(us8*)(Ch + o) = h8;
      *(us8*)(Cl + o) = l8;
    }
  }
}

// ---------------- fused QKV: coalesced Q/K epilogue; V transposed unchanged ----------------
__global__ __launch_bounds__(256) void qkv_m(const ushort_t* __restrict__ Xh, const ushort_t* __restrict__ Xl,
                      const ushort_t* __restrict__ WT4h,
                      const float* __restrict__ bq, const float* __restrict__ bk,
                      const float* __restrict__ bvv,
                      ushort_t* __restrict__ Qh, ushort_t* __restrict__ Ql,
                      ushort_t* __restrict__ Kh, ushort_t* __restrict__ Vth) {
  constexpr int ABYTES = 128 * 32 * 2;
  constexpr int BUF = 2 * ABYTES + 3 * ABYTES;      // 40 KB
  __shared__ __attribute__((aligned(16))) char pool[2 * BUF];   // 80 KB
  const int tid = threadIdx.x;
  const int w = tid >> 6, lane = tid & 63;
  const int wm = w >> 1, wn = w & 1;
  const int kgL = lane >> 4, lr = lane & 15;
  const int row0 = blockIdx.y * 128, col0 = blockIdx.x * 128;

  f32x4 acc[3][4][4];
#pragma unroll
  for (int z = 0; z < 3; ++z)
#pragma unroll
    for (int i = 0; i < 4; ++i)
#pragma unroll
      for (int j = 0; j < 4; ++j) acc[z][i][j] = (f32x4){0.f, 0.f, 0.f, 0.f};

  const int khL = kgL >> 1;
  const int swz = (((kgL & 1) ^ ((lr >> 2) & 1)) << 4);
  const int aB0 = khL * (128 * 32) + (wm * 64 + lr) * 32 + swz;
  const int bB0 = khL * (128 * 32) + (wn * 64 + lr) * 32 + swz;

  const ushort_t* gA_h = Xh + (size_t)row0 * H_;
  const ushort_t* gA_l = Xl + (size_t)row0 * H_;
  const ushort_t* gB0 = WT4h + (size_t)col0 * H_;
  const ushort_t* gB1 = WT4h + (size_t)H_ * H_ + (size_t)col0 * H_;
  const ushort_t* gB2 = WT4h + (size_t)2 * H_ * H_ + (size_t)col0 * H_;

  auto stageall = [&](int k0, char* buf) {
    stage_slice<128>(gA_h + k0, H_, buf);
    stage_slice<128>(gA_l + k0, H_, buf + ABYTES);
    stage_slice<128>(gB0 + k0, H_, buf + 2 * ABYTES);
    stage_slice<128>(gB1 + k0, H_, buf + 3 * ABYTES);
    stage_slice<128>(gB2 + k0, H_, buf + 4 * ABYTES);
  };

  const int nk = H_ / 32;   // 24
  stageall(0, pool);
  for (int k = 0; k < nk; ++k) {
    char* cur = pool + (k & 1) * BUF;
    if (k + 1 < nk) {
      stageall((k + 1) * 32, pool + ((k + 1) & 1) * BUF);
      asm volatile("s_waitcnt vmcnt(10)" ::: "memory");
    } else {
      asm volatile("s_waitcnt vmcnt(0)" ::: "memory");
    }
    __builtin_amdgcn_s_barrier();
    asm volatile("" ::: "memory");

    bf16x8 a_h[4], a_l[4];
#pragma unroll
    for (int fm = 0; fm < 4; ++fm) {
      a_h[fm] = *(const bf16x8*)(cur + aB0 + fm * 512);
      a_l[fm] = *(const bf16x8*)(cur + ABYTES + aB0 + fm * 512);
    }
#pragma unroll
    for (int z = 0; z < 3; ++z) {
      const char* bP = cur + (2 + z) * ABYTES;
      bf16x8 b_h[4];
#pragma unroll
      for (int fn = 0; fn < 4; ++fn) b_h[fn] = *(const bf16x8*)(bP + bB0 + fn * 512);
#pragma unroll
      for (int fm = 0; fm < 4; ++fm)
#pragma unroll
        for (int fn = 0; fn < 4; ++fn) {
          f32x4 c = acc[z][fm][fn];
          c = __builtin_amdgcn_mfma_f32_16x16x32_bf16(a_h[fm], b_h[fn], c, 0, 0, 0);
          c = __builtin_amdgcn_mfma_f32_16x16x32_bf16(a_l[fm], b_h[fn], c, 0, 0, 0);
          acc[z][fm][fn] = c;
        }
    }
    asm volatile("" ::: "memory");
    __builtin_amdgcn_s_barrier();
  }

  const int kg = kgL;
  unsigned* tb = (unsigned*)pool + w * (16 * 68);
  const int row0w = row0 + wm * 64;
  const int col0w = col0 + wn * 64;
  // z = 0 (Q hi/lo), z = 1 (K hi) via coalesced LDS transpose
#pragma unroll
  for (int z = 0; z < 2; ++z) {
    const float* bz = z == 0 ? bq : bk;
#pragma unroll
    for (int fm = 0; fm < 4; ++fm) {
#pragma unroll
      for (int fn = 0; fn < 4; ++fn) {
        const int col = col0w + fn * 16 + lr;
        const float bv = bz[col];
#pragma unroll
        for (int r = 0; r < 4; ++r) {
          float v = acc[z][fm][fn][r] + bv;
          ushort_t h = f2bf(v);
          ushort_t lo = f2bf(v - bf2f(h));
          tb[(kg * 4 + r) * 68 + fn * 16 + lr] = ((unsigned)h << 16) | lo;
        }
      }
#pragma unroll
      for (int it = 0; it < 2; ++it) {
        const int slot = it * 64 + lane;
        const int row16 = slot >> 3, cg = slot & 7;
        unsigned r8[8];
        *(u32x4*)&r8[0] = *(const u32x4*)&tb[row16 * 68 + cg * 8];
        *(u32x4*)&r8[4] = *(const u32x4*)&tb[row16 * 68 + cg * 8 + 4];
        us8 h8, l8;
#pragma unroll
        for (int j = 0; j < 8; ++j) {
          h8[j] = (ushort_t)(r8[j] >> 16);
          l8[j] = (ushort_t)(r8[j] & 0xffffu);
        }
        const int grow = row0w + fm * 16 + row16;
        const size_t o = (size_t)grow * H_ + col0w + cg * 8;
        if (z == 0) {
          *(us8*)(Qh + o) = h8;
          *(us8*)(Ql + o) = l8;
        } else {
          *(us8*)(Kh + o) = h8;
        }
      }
    }
  }
  // z = 2: V transposed [b][h][d][s]
#pragma unroll
  for (int fn = 0; fn < 4; ++fn) {
    const int col = col0w + fn * 16 + lr;
    const float bv = bvv[col];
#pragma unroll
    for (int fm = 0; fm < 4; ++fm) {
      const int rowb = row0w + fm * 16 + kg * 4;
      us4 h4;
#pragma unroll
      for (int r = 0; r < 4; ++r) h4[r] = f2bf(acc[2][fm][fn][r] + bv);
      const int bb2 = rowb >> 8, s0 = rowb & 255;
      const int hh2 = col >> 6, d = col & 63;
      *(us4*)(Vth + ((size_t)(bb2 * NH_ + hh2) * DH_ + d) * S_ + s0) = h4;
    }
  }
}

// ---------------- MFMA flash attention, double-buffered K/V ----------------
__global__ __launch_bounds__(256, 3) void attn_mfma(
    const ushort_t* __restrict__ Qh, const ushort_t* __restrict__ Ql,
    const ushort_t* __restrict__ Kh, const ushort_t* __restrict__ Vth,
    const int* __restrict__ amask,
    ushort_t* __restrict__ Oh, ushort_t* __restrict__ Ol) {
  const int bid = blockIdx.x;
  const int qt = bid / 192;
  const int gh = bid - qt * 192;
  const int b = gh / NH_;
  const int h = gh - b * NH_;
  __shared__ __attribute__((aligned(16))) ushort_t sKh[2][64 * 64];
  __shared__ __attribute__((aligned(16))) ushort_t sVh[2][64 * 64];
  __shared__ __attribute__((aligned(16))) unsigned sP[4][16 * 68];
  __shared__ float sBias[2][64];
  const int tid = threadIdx.x;
  const int w = tid >> 6, lane = tid & 63;
  const int kg = lane >> 4, lr = lane & 15;

  const int qrow = b * S_ + qt * 64 + w * 16 + lr;
  bf16x8 qfh[2], qfl[2];
#pragma unroll
  for (int ds2 = 0; ds2 < 2; ++ds2) {
    const size_t off = (size_t)qrow * H_ + h * DH_ + ds2 * 32 + kg * 8;
    qfh[ds2] = *(const bf16x8*)(Qh + off);
    qfl[ds2] = *(const bf16x8*)(Ql + off);
  }

  f32x4 ctx[4];
#pragma unroll
  for (int i = 0; i < 4; ++i) ctx[i] = (f32x4){0.f, 0.f, 0.f, 0.f};
  float mrow[4], lrw[4];
#pragma unroll
  for (int r = 0; r < 4; ++r) { mrow[r] = -1e30f; lrw[r] = 0.f; }

  unsigned* sPw = &sP[w][0];

  auto stageKV = [&](int kt, int bufi) {
#pragma unroll
    for (int i = 0; i < 2; ++i) {
      const int v = tid + i * 256;
      const int row = v >> 3;
      const int c16 = (v & 7) ^ (row & 7);
      const size_t kgl = (size_t)(b * S_ + kt * 64 + row) * H_ + h * DH_ + c16 * 8;
      gload16(Kh + kgl, (char*)&sKh[bufi][0] + v * 16);
      const size_t vgl = (size_t)((b * NH_ + h) * DH_ + row) * S_ + kt * 64 + c16 * 8;
      gload16(Vth + vgl, (char*)&sVh[bufi][0] + v * 16);
    }
    if (tid < 64) sBias[bufi][tid] = (amask[b * S_ + kt * 64 + tid] > 0) ? 0.f : -1e9f;
  };

  stageKV(0, 0);
  for (int kt = 0; kt < 4; ++kt) {
    const int bi = kt & 1;
    if (kt < 3) {
      stageKV(kt + 1, bi ^ 1);
      asm volatile("s_waitcnt vmcnt(4) lgkmcnt(0)" ::: "memory");
    } else {
      asm volatile("s_waitcnt vmcnt(0) lgkmcnt(0)" ::: "memory");
    }
    __builtin_amdgcn_s_barrier();
    asm volatile("" ::: "memory");

    // QK^T
    f32x4 sc[4];
#pragma unroll
    for (int kf = 0; kf < 4; ++kf) sc[kf] = (f32x4){0.f, 0.f, 0.f, 0.f};
#pragma unroll
    for (int kf = 0; kf < 4; ++kf) {
      const int krow = kf * 16 + lr;
#pragma unroll
      for (int ds2 = 0; ds2 < 2; ++ds2) {
        const int cb = (ds2 * 64 + kg * 16) ^ ((krow & 7) << 4);
        const bf16x8 kvh = *(const bf16x8*)((const char*)&sKh[bi][0] + krow * 128 + cb);
        sc[kf] = __builtin_amdgcn_mfma_f32_16x16x32_bf16(qfh[ds2], kvh, sc[kf], 0, 0, 0);
        sc[kf] = __builtin_amdgcn_mfma_f32_16x16x32_bf16(qfl[ds2], kvh, sc[kf], 0, 0, 0);
      }
    }
    float bsv[4];
#pragma unroll
    for (int kf = 0; kf < 4; ++kf) bsv[kf] = sBias[bi][kf * 16 + lr];

#pragma unroll
    for (int r = 0; r < 4; ++r) {
      float sv[4];
      float tmax = -1e30f;
#pragma unroll
      for (int kf = 0; kf < 4; ++kf) {
        sv[kf] = sc[kf][r] * 0.125f + bsv[kf];
        tmax = fmaxf(tmax, sv[kf]);
      }
#pragma unroll
      for (int o = 8; o > 0; o >>= 1) tmax = fmaxf(tmax, __shfl_xor(tmax, o, 64));
      const float mnew = fmaxf(mrow[r], tmax);
      const float corr = expf(mrow[r] - mnew);
      float ls = 0.f;
      const int qoff = (kg * 4 + r) * 68;
#pragma unroll
      for (int kf = 0; kf < 4; ++kf) {
        const float pe = expf(sv[kf] - mnew);
        ls += pe;
        const ushort_t hi = f2bf(pe);
        const ushort_t lo = f2bf(pe - bf2f(hi));
        sPw[qoff + kf * 16 + lr] = ((unsigned)hi << 16) | lo;
      }
#pragma unroll
      for (int o = 8; o > 0; o >>= 1) ls += __shfl_xor(ls, o, 64);
      lrw[r] = lrw[r] * corr + ls;
      mrow[r] = mnew;
#pragma unroll
      for (int df = 0; df < 4; ++df) ctx[df][r] *= corr;
    }

    // PV
#pragma unroll
    for (int ks = 0; ks < 2; ++ks) {
      unsigned w8[8];
      *(u32x4*)&w8[0] = *(const u32x4*)(sPw + lr * 68 + ks * 32 + kg * 8);
      *(u32x4*)&w8[4] = *(const u32x4*)(sPw + lr * 68 + ks * 32 + kg * 8 + 4);
      union { bf16x8 v; ushort_t u[8]; } ph, pl;
#pragma unroll
      for (int j = 0; j < 8; ++j) { ph.u[j] = (ushort_t)(w8[j] >> 16); pl.u[j] = (ushort_t)(w8[j] & 0xffffu); }
#pragma unroll
      for (int df = 0; df < 4; ++df) {
        const int vrow = df * 16 + lr;
        const int cb = (ks * 64 + kg * 16) ^ ((vrow & 7) << 4);
        const bf16x8 vvh = *(const bf16x8*)((const char*)&sVh[bi][0] + vrow * 128 + cb);
        ctx[df] = __builtin_amdgcn_mfma_f32_16x16x32_bf16(ph.v, vvh, ctx[df], 0, 0, 0);
        ctx[df] = __builtin_amdgcn_mfma_f32_16x16x32_bf16(pl.v, vvh, ctx[df], 0, 0, 0);
      }
    }
    asm volatile("" ::: "memory");
    __builtin_amdgcn_s_barrier();
  }

#pragma unroll
  for (int r = 0; r < 4; ++r) {
    const float inv = 1.f / lrw[r];
    const int tok = b * S_ + qt * 64 + w * 16 + kg * 4 + r;
#pragma unroll
    for (int df = 0; df < 4; ++df) {
      const float v = ctx[df][r] * inv;
      const ushort_t hi = f2bf(v);
      const size_t o = (size_t)tok * H_ + h * DH_ + df * 16 + lr;
      Oh[o] = hi;
      Ol[o] = f2bf(v - bf2f(hi));
    }
  }
}

// ---------------- CRF v5: readlane broadcast, zero-LDS recurrence ----------------
__global__ __launch_bounds__(128) void crf_kernel(const float* __restrict__ emis, const int* __restrict__ tags,
                          const int* __restrict__ amask,
                          const float* __restrict__ crf_start, const float* __restrict__ crf_end,
                          const float* __restrict__ trans,
                          float* __restrict__ partial, float* __restrict__ out) {
  const int b = blockIdx.x;
  const int tid = threadIdx.x;
  const int wv = tid >> 6;
  const int lane = tid & 63;
  __shared__ float sE[S_ * T_];
  __shared__ float sM[S_];
  __shared__ float trs[T_ * T_];
  __shared__ unsigned char hist[S_ - 1][16];
  __shared__ float pathf[S_];
  for (int i = tid; i < S_ * T_; i += 128) {
    const int s = i / T_, t = i - s * T_;
    sE[i] = emis[((size_t)s * B_ + b) * T_ + t];
  }
  for (int i = tid; i < S_; i += 128) sM[i] = (float)amask[b * S_ + i];
  for (int i = tid; i < T_ * T_; i += 128) trs[i] = trans[i];
  __syncthreads();

  const int t = lane;
  const bool act = t < T_;
  float trc[T_];
#pragma unroll
  for (int p = 0; p < T_; ++p) trc[p] = act ? trs[p * T_ + t] : 0.f;

  if (wv == 0) {
    float alpha = act ? crf_start[t] + sE[t] : 0.f;
    for (int s = 1; s < S_; ++s) {
      float ap[T_];
#pragma unroll
      for (int p = 0; p < T_; ++p) ap[p] = rdlane(alpha, p);
      if (act) {
        const float e = sE[s * T_ + t];
        float v[T_];
#pragma unroll
        for (int p = 0; p < T_; ++p) v[p] = ap[p] + trc[p];
        float m0 = fmaxf(fmaxf(v[0], v[1]), fmaxf(v[2], v[3]));
        float m1 = fmaxf(fmaxf(v[4], v[5]), fmaxf(v[6], v[7]));
        const float mx = fmaxf(fmaxf(m0, m1), v[8]);
        float sum = 0.f;
#pragma unroll
        for (int p = 0; p < T_; ++p) sum += __expf(v[p] - mx);
        const float na = mx + __logf(sum) + e;
        if (sM[s] > 0.f) alpha = na;
      }
    }
    float nsum = 0.f;
    int len = 0;
#pragma unroll
    for (int j = 0; j < 4; ++j) {
      const int s = lane + j * 64;
      const int mk = (sM[s] > 0.f) ? 1 : 0;
      len += mk;
      if (s >= 1 && mk) {
        const int tc = tags[b * S_ + s], tp = tags[b * S_ + s - 1];
        nsum += trs[tp * T_ + tc] + sE[s * T_ + tc];
      }
    }
#pragma unroll
    for (int o = 32; o > 0; o >>= 1) {
      nsum += __shfl_xor(nsum, o, 64);
      len += __shfl_xor(len, o, 64);
    }
    const float fz = act ? alpha + crf_end[t] : -1e30f;
    float zp[T_];
#pragma unroll
    for (int p = 0; p < T_; ++p) zp[p] = rdlane(fz, p);
    if (lane == 0) {
      float mx = -1e30f;
#pragma unroll
      for (int p = 0; p < T_; ++p) mx = fmaxf(mx, zp[p]);
      float sum = 0.f;
#pragma unroll
      for (int p = 0; p < T_; ++p) sum += __expf(zp[p] - mx);
      const float logZ = mx + __logf(sum);
      const int tg0 = tags[b * S_];
      const float score = nsum + crf_start[tg0] + sE[tg0] + crf_end[tags[b * S_ + len - 1]];
      partial[b] = score - logZ;
    }
  } else {
    float vit = act ? crf_start[t] + sE[t] : 0.f;
    for (int s = 1; s < S_; ++s) {
      float vp[T_];
#pragma unroll
      for (int p = 0; p < T_; ++p) vp[p] = rdlane(vit, p);
      if (act) {
        const float e = sE[s * T_ + t];
        float best = -1e30f; int bi = 0;
#pragma unroll
        for (int p = 0; p < T_; ++p) {
          const float scv = vp[p] + trc[p];
          if (scv > best) { best = scv; bi = p; }
        }
        if (sM[s] > 0.f) {
          vit = best + e;
          hist[s - 1][t] = (unsigned char)bi;
        } else {
          hist[s - 1][t] = (unsigned char)t;
        }
      }
    }
    const float fv = act ? vit + crf_end[t] : -1e30f;
    float wp[T_];
#pragma unroll
    for (int p = 0; p < T_; ++p) wp[p] = rdlane(fv, p);
    if (lane == 0) {
      float best = -1e30f; int lastTag = 0;
#pragma unroll
      for (int p = 0; p < T_; ++p) {
        if (wp[p] > best) { best = wp[p]; lastTag = p; }
      }
      int tc = lastTag;
      pathf[S_ - 1] = (float)tc;
      for (int i = S_ - 2; i >= 0; --i) {
        tc = hist[i][tc];
        pathf[i] = (float)tc;
      }
    }
  }
  __syncthreads();
#pragma unroll
  for (int j = 0; j < 2; ++j) {
    const int s = tid + j * 128;
    out[1 + b * S_ + s] = pathf[s];
  }
}

__global__ __launch_bounds__(64) void crf_final(const float* __restrict__ partial, float* __restrict__ out) {
  const int lane = threadIdx.x;
  float v = (lane < B_) ? partial[lane] : 0.f;
#pragma unroll
  for (int o = 32; o > 0; o >>= 1) v += __shfl_xor(v, o, 64);
  if (lane == 0) out[0] = -(v * (1.f / B_));
}

extern "C" void kernel_launch(void* const* d_in, const int* in_sizes, int n_in,
                              void* d_out, int out_size, void* d_ws, size_t ws_size,
                              hipStream_t stream) {
  const int* input_ids = (const int*)d_in[0];
  const int* token_type_ids = (const int*)d_in[1];
  const int* attention_mask = (const int*)d_in[2];
  const int* tags = (const int*)d_in[3];
  const float* word_emb = (const float*)d_in[4];
  const float* pos_emb = (const float*)d_in[5];
  const float* type_emb = (const float*)d_in[6];
  const float* emb_ln_g = (const float*)d_in[7];
  const float* emb_ln_b = (const float*)d_in[8];
  const float* Wq = (const float*)d_in[9];
  const float* bq = (const float*)d_in[10];
  const float* Wk = (const float*)d_in[11];
  const float* bk = (const float*)d_in[12];
  const float* Wv = (const float*)d_in[13];
  const float* bv = (const float*)d_in[14];
  const float* Wo = (const float*)d_in[15];
  const float* bo = (const float*)d_in[16];
  const float* ln1_g = (const float*)d_in[17];
  const float* ln1_b = (const float*)d_in[18];
  const float* W1 = (const float*)d_in[19];
  const float* b1 = (const float*)d_in[20];
  const float* W2 = (const float*)d_in[21];
  const float* b2 = (const float*)d_in[22];
  const float* ln2_g = (const float*)d_in[23];
  const float* ln2_b = (const float*)d_in[24];
  const float* dense_W = (const float*)d_in[25];
  const float* dense_b = (const float*)d_in[26];
  const float* crf_start = (const float*)d_in[27];
  const float* crf_end = (const float*)d_in[28];
  const float* crf_trans = (const float*)d_in[29];

  constexpr size_t NTOK = (size_t)B_ * S_;        // 4096
  constexpr size_t XSZ = NTOK * H_;               // 3,145,728
  constexpr size_t WT4SZ = (size_t)4 * H_ * H_;   // 2,359,296
  constexpr size_t WFSZ = (size_t)H_ * FF_;       // 2,359,296

  char* p = (char*)d_ws;
  float* TMP = (float*)p;          p += XSZ * 4;
  char* UN = p;                    p += 8 * XSZ * 2;     // 50.33 MB union
  ushort_t* Qh = (ushort_t*)UN;
  ushort_t* Ql = Qh + XSZ;
  ushort_t* Kh = Ql + XSZ;
  ushort_t* Vth = Kh + XSZ;
  ushort_t* CTXh = Vth + XSZ;
  ushort_t* CTXl = CTXh + XSZ;
  ushort_t* FFh = (ushort_t*)UN;                        // aliases QKV after dead
  ushort_t* FFl = FFh + NTOK * FF_;
  ushort_t* Xh = (ushort_t*)p;     p += XSZ * 2;
  ushort_t* Xl = (ushort_t*)p;     p += XSZ * 2;
  ushort_t* WT4h2 = (ushort_t*)p;  p += WT4SZ * 2 * 2;  // double-buffered
  ushort_t* W1th2 = (ushort_t*)p;  p += WFSZ * 2 * 2;
  ushort_t* W2th2 = (ushort_t*)p;  p += WFSZ * 2 * 2;
  float* EM = (float*)p;           p += (size_t)S_ * B_ * T_ * 4;
  float* PART = (float*)p;         p += B_ * 4;

  emb_ln_kernel<<<dim3(4096), dim3(256), 0, stream>>>(input_ids, token_type_ids, word_emb, pos_emb,
                                                      type_emb, emb_ln_g, emb_ln_b, Xh, Xl);
  // layer 0 weights into parity 0
  wprep_k<<<dim3(1728), dim3(256), 0, stream>>>(Wq, Wk, Wv, Wo, W1, W2, WT4h2, W1th2, W2th2);

  for (int l = 0; l < L_; ++l) {
    const int pr = l & 1, pn = (l + 1) & 1;
    ushort_t* WT4h = WT4h2 + (size_t)pr * WT4SZ;
    ushort_t* W1th = W1th2 + (size_t)pr * WFSZ;
    ushort_t* W2th = W2th2 + (size_t)pr * WFSZ;
    const bool hasNext = (l + 1 < L_);
    const size_t wo_n = (size_t)(l + 1) * H_ * H_;

    qkv_m<<<dim3(6, 32), dim3(256), 0, stream>>>(Xh, Xl, WT4h, bq + (size_t)l * H_,
                                                 bk + (size_t)l * H_, bv + (size_t)l * H_,
                                                 Qh, Ql, Kh, Vth);
    attn_mfma<<<dim3(768), dim3(256), 0, stream>>>(Qh, Ql, Kh, Vth, attention_mask, CTXh, CTXl);
    mgemm<128, 128, 32, 0><<<dim3(6, 32), dim3(256), 0, stream>>>(
        CTXh, CTXl, WT4h + (size_t)3 * H_ * H_,
        bo + (size_t)l * H_, TMP, nullptr, nullptr, H_, H_);
    ln_kernel<<<dim3(4096), dim3(256), 0, stream>>>(Xh, Xl, TMP, ln1_g + (size_t)l * H_,
                                                    ln1_b + (size_t)l * H_, Xh, Xl);
    ff1_fused<<<dim3(12, 32 + 144), dim3(256), 0, stream>>>(
        Xh, Xl, W1th, b1 + (size_t)l * FF_, FFh, FFl,
        hasNext ? Wq + wo_n : nullptr, Wk + wo_n, Wv + wo_n, Wo + wo_n,
        W1 + (size_t)(l + 1) * WFSZ, W2 + (size_t)(l + 1) * WFSZ,
        WT4h2 + (size_t)pn * WT4SZ, W1th2 + (size_t)pn * WFSZ, W2th2 + (size_t)pn * WFSZ);
    mgemm<128, 128, 32, 0><<<dim3(6, 32), dim3(256), 0, stream>>>(
        FFh, FFl, W2th, b2 + (size_t)l * H_, TMP, nullptr, nullptr, H_, FF_);
    if (l + 1 < L_) {
      ln_kernel<<<dim3(4096), dim3(256), 0, stream>>>(Xh, Xl, TMP, ln2_g + (size_t)l * H_,
                                                      ln2_b + (size_t)l * H_, Xh, Xl);
    } else {
      ln_emis_kernel<<<dim3(4096), dim3(256), 0, stream>>>(Xh, Xl, TMP, ln2_g + (size_t)l * H_,
                                                           ln2_b + (size_t)l * H_, dense_W,
                                                           dense_b, EM);
    }
  }

  crf_kernel<<<dim3(B_), dim3(128), 0, stream>>>(EM, tags, attention_mask, crf_start, crf_end,
                                                 crf_trans, PART, (float*)d_out);
  crf_final<<<dim3(1), dim3(64), 0, stream>>>(PART, (float*)d_out);
}

// Round 16
// 2795.047 us; speedup vs baseline: 1.1320x; 1.0961x over previous
//
#include <hip/hip_runtime.h>
#include <math.h>

#define B_ 16
#define S_ 256
#define H_ 768
#define L_ 12
#define NH_ 12
#define DH_ 64
#define FF_ 3072
#define T_ 9

typedef unsigned short ushort_t;
typedef __attribute__((ext_vector_type(8))) __bf16 bf16x8;
typedef __attribute__((ext_vector_type(4))) float f32x4;
typedef __attribute__((ext_vector_type(4))) unsigned short us4;
typedef __attribute__((ext_vector_type(8))) unsigned short us8;
typedef __attribute__((ext_vector_type(4))) unsigned int u32x4;

__device__ __forceinline__ ushort_t f2bf(float f) {
  union { float f; unsigned u; } v; v.f = f;
  unsigned r = v.u + 0x7FFFu + ((v.u >> 16) & 1u);
  return (ushort_t)(r >> 16);
}
__device__ __forceinline__ float bf2f(ushort_t h) {
  union { unsigned u; float f; } v; v.u = ((unsigned)h) << 16;
  return v.f;
}
__device__ __forceinline__ float rdlane(float v, int l) {
  union { float f; int i; } u; u.f = v;
  union { int i; float f; } o; o.i = __builtin_amdgcn_readlane(u.i, l);
  return o.f;
}
__device__ __forceinline__ void gload16(const void* g, void* l) {
  __builtin_amdgcn_global_load_lds((const __attribute__((address_space(1))) void*)g,
                                   (__attribute__((address_space(3))) void*)l, 16, 0, 0);
}

// ---------------- fused embedding sum + layernorm (hi/lo out only) ----------------
__global__ __launch_bounds__(256) void emb_ln_kernel(const int* __restrict__ ids, const int* __restrict__ tt,
                              const float* __restrict__ we, const float* __restrict__ pe,
                              const float* __restrict__ te, const float* __restrict__ g,
                              const float* __restrict__ bb,
                              ushort_t* __restrict__ oh, ushort_t* __restrict__ ol) {
  const int token = blockIdx.x;
  const int tid = threadIdx.x;
  const int s = token & (S_ - 1);
  const int id = ids[token];
  const int t2 = tt[token];
  float x[3];
  float sum = 0.f;
#pragma unroll
  for (int i = 0; i < 3; ++i) {
    int d = tid + i * 256;
    x[i] = we[(size_t)id * H_ + d] + pe[(size_t)s * H_ + d] + te[(size_t)t2 * H_ + d];
    sum += x[i];
  }
  __shared__ float red[4];
#pragma unroll
  for (int o = 32; o > 0; o >>= 1) sum += __shfl_xor(sum, o, 64);
  const int wid = tid >> 6, lane = tid & 63;
  if (lane == 0) red[wid] = sum;
  __syncthreads();
  const float mean = (red[0] + red[1] + red[2] + red[3]) * (1.f / H_);
  float vs = 0.f;
#pragma unroll
  for (int i = 0; i < 3; ++i) { float dv = x[i] - mean; vs += dv * dv; }
#pragma unroll
  for (int o = 32; o > 0; o >>= 1) vs += __shfl_xor(vs, o, 64);
  __syncthreads();
  if (lane == 0) red[wid] = vs;
  __syncthreads();
  const float var = (red[0] + red[1] + red[2] + red[3]) * (1.f / H_);
  const float inv = rsqrtf(var + 1e-12f);
  ushort_t* hp = oh + (size_t)token * H_;
  ushort_t* lp = ol + (size_t)token * H_;
#pragma unroll
  for (int i = 0; i < 3; ++i) {
    int d = tid + i * 256;
    float y = (x[i] - mean) * inv * g[d] + bb[d];
    ushort_t h = f2bf(y);
    hp[d] = h;
    lp[d] = f2bf(y - bf2f(h));
  }
}

// ---------------- layernorm: base from hi/lo pair + f32 delta -> hi/lo out ----------------
__global__ __launch_bounds__(256) void ln_kernel(const ushort_t* __restrict__ bh, const ushort_t* __restrict__ bl,
                          const float* __restrict__ delta,
                          const float* __restrict__ g, const float* __restrict__ bb,
                          ushort_t* __restrict__ oh, ushort_t* __restrict__ ol) {
  const int token = blockIdx.x;
  const int tid = threadIdx.x;
  const ushort_t* bhp = bh + (size_t)token * H_;
  const ushort_t* blp = bl + (size_t)token * H_;
  const float* dp = delta + (size_t)token * H_;
  float x[3];
  float s = 0.f;
#pragma unroll
  for (int i = 0; i < 3; ++i) {
    int d = tid + i * 256;
    x[i] = bf2f(bhp[d]) + bf2f(blp[d]) + dp[d];
    s += x[i];
  }
  __shared__ float red[4];
#pragma unroll
  for (int o = 32; o > 0; o >>= 1) s += __shfl_xor(s, o, 64);
  const int wid = tid >> 6, lane = tid & 63;
  if (lane == 0) red[wid] = s;
  __syncthreads();
  const float mean = (red[0] + red[1] + red[2] + red[3]) * (1.f / H_);
  float vs = 0.f;
#pragma unroll
  for (int i = 0; i < 3; ++i) { float dv = x[i] - mean; vs += dv * dv; }
#pragma unroll
  for (int o = 32; o > 0; o >>= 1) vs += __shfl_xor(vs, o, 64);
  __syncthreads();
  if (lane == 0) red[wid] = vs;
  __syncthreads();
  const float var = (red[0] + red[1] + red[2] + red[3]) * (1.f / H_);
  const float inv = rsqrtf(var + 1e-12f);
  ushort_t* hp = oh + (size_t)token * H_;
  ushort_t* lp = ol + (size_t)token * H_;
#pragma unroll
  for (int i = 0; i < 3; ++i) {
    int d = tid + i * 256;
    float y = (x[i] - mean) * inv * g[d] + bb[d];
    ushort_t h = f2bf(y);
    hp[d] = h;
    lp[d] = f2bf(y - bf2f(h));
  }
}

// ---------------- final layernorm + emissions fused ----------------
__global__ __launch_bounds__(256) void ln_emis_kernel(const ushort_t* __restrict__ bh, const ushort_t* __restrict__ bl,
                               const float* __restrict__ delta,
                               const float* __restrict__ g, const float* __restrict__ bb,
                               const float* __restrict__ W, const float* __restrict__ wbias,
                               float* __restrict__ E) {
  const int token = blockIdx.x;
  const int tid = threadIdx.x;
  __shared__ float sW[H_ * T_];     // 27 KB
  __shared__ float red[4];
  __shared__ float wred[4][12];
  for (int i = tid; i < H_ * T_; i += 256) sW[i] = W[i];

  const ushort_t* bhp = bh + (size_t)token * H_;
  const ushort_t* blp = bl + (size_t)token * H_;
  const float* dp = delta + (size_t)token * H_;
  float x[3];
  float s = 0.f;
#pragma unroll
  for (int i = 0; i < 3; ++i) {
    int d = tid + i * 256;
    x[i] = bf2f(bhp[d]) + bf2f(blp[d]) + dp[d];
    s += x[i];
  }
#pragma unroll
  for (int o = 32; o > 0; o >>= 1) s += __shfl_xor(s, o, 64);
  const int wid = tid >> 6, lane = tid & 63;
  if (lane == 0) red[wid] = s;
  __syncthreads();
  const float mean = (red[0] + red[1] + red[2] + red[3]) * (1.f / H_);
  float vs = 0.f;
#pragma unroll
  for (int i = 0; i < 3; ++i) { float dv = x[i] - mean; vs += dv * dv; }
#pragma unroll
  for (int o = 32; o > 0; o >>= 1) vs += __shfl_xor(vs, o, 64);
  __syncthreads();
  if (lane == 0) red[wid] = vs;
  __syncthreads();
  const float var = (red[0] + red[1] + red[2] + red[3]) * (1.f / H_);
  const float inv = rsqrtf(var + 1e-12f);

  float acc9[T_];
#pragma unroll
  for (int t = 0; t < T_; ++t) acc9[t] = 0.f;
#pragma unroll
  for (int i = 0; i < 3; ++i) {
    int d = tid + i * 256;
    float y = (x[i] - mean) * inv * g[d] + bb[d];
    const float* wr = sW + d * T_;
#pragma unroll
    for (int t = 0; t < T_; ++t) acc9[t] = fmaf(y, wr[t], acc9[t]);
  }
#pragma unroll
  for (int o = 32; o > 0; o >>= 1)
#pragma unroll
    for (int t = 0; t < T_; ++t) acc9[t] += __shfl_xor(acc9[t], o, 64);
  if (lane == 0) {
#pragma unroll
    for (int t = 0; t < T_; ++t) wred[wid][t] = acc9[t];
  }
  __syncthreads();
  if (tid < T_) {
    const float v = wred[0][tid] + wred[1][tid] + wred[2][tid] + wred[3][tid] + wbias[tid];
    const int b2 = token >> 8, s2 = token & 255;
    E[((size_t)s2 * B_ + b2) * T_ + tid] = v;
  }
}

// ---------------- weight transpose + bf16 round: src[K][N] f32 -> dst[N][K] ----------------
__device__ __forceinline__ void transpose_core(float (*t)[65], const float* __restrict__ src,
                                               ushort_t* __restrict__ dh,
                                               int K, int N, int n0, int k0) {
  const int tid = threadIdx.x;
#pragma unroll
  for (int i = 0; i < 16; ++i) {
    int lin = tid + i * 256;
    int kk = lin >> 6, nn = lin & 63;
    t[kk][nn] = src[(size_t)(k0 + kk) * N + n0 + nn];
  }
  __syncthreads();
#pragma unroll
  for (int i = 0; i < 16; ++i) {
    int lin = tid + i * 256;
    int nn = lin >> 6, kk = lin & 63;
    dh[(size_t)(n0 + nn) * K + k0 + kk] = f2bf(t[kk][nn]);
  }
}

__device__ __forceinline__ void wprep_dispatch(float (*t)[65], int wid,
                        const float* Wq, const float* Wk, const float* Wv, const float* Wo,
                        const float* W1, const float* W2,
                        ushort_t* WT4h, ushort_t* W1th, ushort_t* W2th) {
  if (wid < 576) {
    const int z = wid / 144, r = wid - z * 144;
    const int x = r % 12, y = r / 12;
    const float* src = z == 0 ? Wq : (z == 1 ? Wk : (z == 2 ? Wv : Wo));
    transpose_core(t, src, WT4h + (size_t)z * H_ * H_, H_, H_, x * 64, y * 64);
  } else if (wid < 1152) {
    const int i = wid - 576;
    const int x = i % 48, y = i / 48;
    transpose_core(t, W1, W1th, H_, FF_, x * 64, y * 64);
  } else {
    const int i = wid - 1152;
    const int x = i % 12, y = i / 12;
    transpose_core(t, W2, W2th, FF_, H_, x * 64, y * 64);
  }
}

__global__ __launch_bounds__(256) void wprep_k(const float* __restrict__ Wq, const float* __restrict__ Wk,
                        const float* __restrict__ Wv, const float* __restrict__ Wo,
                        const float* __restrict__ W1, const float* __restrict__ W2,
                        ushort_t* __restrict__ WT4h,
                        ushort_t* __restrict__ W1th, ushort_t* __restrict__ W2th) {
  __shared__ float t[64][65];
  wprep_dispatch(t, blockIdx.x, Wq, Wk, Wv, Wo, W1, W2, WT4h, W1th, W2th);
}

// ---------------- conflict-free staging (proven mapping), one 32-K slice ----------------
template <int R>
__device__ __forceinline__ void stage_slice(const ushort_t* __restrict__ gsrc, int K, char* lds) {
  const int tid = threadIdx.x;
  constexpr int NIT = (R * 4) / 256;
#pragma unroll
  for (int i = 0; i < NIT; ++i) {
    const int v = tid + i * 256;
    const int kh = v / (2 * R);
    const int r2 = v & (2 * R - 1);
    const int row = r2 >> 1;
    const int kg = (kh << 1) | ((r2 & 1) ^ ((row >> 2) & 1));
    gload16(gsrc + (size_t)row * K + kg * 8, lds + (i * 256 + (tid & 192)) * 16);
  }
}

// ---------------- split-A MFMA GEMM core, double-buffered: acc = (Ah+Al) * Bh^T ----------------
template <int BM, int BN, int BK>
__device__ __forceinline__ void mgemm_acc(
    const ushort_t* __restrict__ Ah, const ushort_t* __restrict__ Al,
    const ushort_t* __restrict__ Bth,
    int K, f32x4 (&acc)[BM / 32][BN / 32], char* pool, int row0, int col0) {
  constexpr int FM = BM / 32;
  constexpr int FN = BN / 32;
  constexpr int ABYTES = BM * BK * 2;
  constexpr int BBYTES = BN * BK * 2;
  constexpr int BUF = 2 * ABYTES + BBYTES;
  constexpr int NL = (8 * BM + 4 * BN) / 256;
  const int tid = threadIdx.x;
  const int w = tid >> 6, lane = tid & 63;
  const int wm = w >> 1, wn = w & 1;
  const int kgL = lane >> 4, lr = lane & 15;

#pragma unroll
  for (int i = 0; i < FM; ++i)
#pragma unroll
    for (int j = 0; j < FN; ++j) acc[i][j] = (f32x4){0.f, 0.f, 0.f, 0.f};

  const int khL = kgL >> 1;
  const int swz = (((kgL & 1) ^ ((lr >> 2) & 1)) << 4);
  const int aB0 = khL * (BM * 32) + (wm * (BM / 2) + lr) * 32 + swz;
  const int bB0 = khL * (BN * 32) + (wn * (BN / 2) + lr) * 32 + swz;

  const ushort_t* gA_h = Ah + (size_t)row0 * K;
  const ushort_t* gA_l = Al + (size_t)row0 * K;
  const ushort_t* gB_h = Bth + (size_t)col0 * K;

  auto stageall = [&](int k0, char* buf) {
#pragma unroll
    for (int c = 0; c < BK / 32; ++c) {
      stage_slice<BM>(gA_h + k0 + c * 32, K, buf + c * BM * 64);
      stage_slice<BM>(gA_l + k0 + c * 32, K, buf + ABYTES + c * BM * 64);
      stage_slice<BN>(gB_h + k0 + c * 32, K, buf + 2 * ABYTES + c * BN * 64);
    }
  };

  const int nk = K / BK;
  stageall(0, pool);
  for (int k = 0; k < nk; ++k) {
    char* cur = pool + (k & 1) * BUF;
    if (k + 1 < nk) {
      stageall((k + 1) * BK, pool + ((k + 1) & 1) * BUF);
      if constexpr (NL == 6) {
        asm volatile("s_waitcnt vmcnt(6)" ::: "memory");
      } else if constexpr (NL == 8) {
        asm volatile("s_waitcnt vmcnt(8)" ::: "memory");
      } else {
        asm volatile("s_waitcnt vmcnt(0)" ::: "memory");
      }
    } else {
      asm volatile("s_waitcnt vmcnt(0)" ::: "memory");
    }
    __builtin_amdgcn_s_barrier();
    asm volatile("" ::: "memory");

#pragma unroll
    for (int ks = 0; ks < BK / 32; ++ks) {
      const char* aP = cur + ks * BM * 64;
      const char* bP = cur + 2 * ABYTES + ks * BN * 64;
      bf16x8 a_h[FM], a_l[FM], b_h[FN];
#pragma unroll
      for (int fm = 0; fm < FM; ++fm) {
        a_h[fm] = *(const bf16x8*)(aP + aB0 + fm * 512);
        a_l[fm] = *(const bf16x8*)(aP + ABYTES + aB0 + fm * 512);
      }
#pragma unroll
      for (int fn = 0; fn < FN; ++fn) {
        b_h[fn] = *(const bf16x8*)(bP + bB0 + fn * 512);
      }
#pragma unroll
      for (int fm = 0; fm < FM; ++fm)
#pragma unroll
        for (int fn = 0; fn < FN; ++fn) {
          f32x4 c = acc[fm][fn];
          c = __builtin_amdgcn_mfma_f32_16x16x32_bf16(a_h[fm], b_h[fn], c, 0, 0, 0);
          c = __builtin_amdgcn_mfma_f32_16x16x32_bf16(a_l[fm], b_h[fn], c, 0, 0, 0);
          acc[fm][fn] = c;
        }
    }
    asm volatile("" ::: "memory");
    __builtin_amdgcn_s_barrier();
  }
}

// generic GEMM, f32 out, coalesced epilogue, XCD-swizzled grid (must be (6,32))
template <int BM, int BN, int BK, int EPI>
__global__ __launch_bounds__(256, 3) void mgemm(const ushort_t* __restrict__ Ah, const ushort_t* __restrict__ Al,
                      const ushort_t* __restrict__ Bth,
                      const float* __restrict__ bias, float* __restrict__ Cf,
                      ushort_t* __restrict__ Ch, ushort_t* __restrict__ Cl, int N, int K) {
  __shared__ __attribute__((aligned(16))) char pool[2 * (2 * BM * BK + BN * BK) * 2];
  // bijective XCD swizzle: contiguous work per XCD shares A row-panels
  const int ngem = gridDim.x * gridDim.y;
  const int bid = blockIdx.x + blockIdx.y * gridDim.x;
  const int cpx = ngem >> 3;
  const int widb = (bid & 7) * cpx + (bid >> 3);
  const int bx = widb % gridDim.x, by = widb / gridDim.x;
  const int row0 = by * BM, col0 = bx * BN;
  f32x4 acc[BM / 32][BN / 32];
  mgemm_acc<BM, BN, BK>(Ah, Al, Bth, K, acc, pool, row0, col0);
  const int tid = threadIdx.x;
  const int w = tid >> 6, lane = tid & 63;
  const int wm = w >> 1, wn = w & 1;
  const int kg = lane >> 4, lr = lane & 15;
  float* tb = (float*)pool + w * (16 * 68);
  const int row0w = row0 + wm * (BM / 2);
  const int col0w = col0 + wn * (BN / 2);
#pragma unroll
  for (int fm = 0; fm < BM / 32; ++fm) {
#pragma unroll
    for (int fn = 0; fn < BN / 32; ++fn) {
      const int col = col0w + fn * 16 + lr;
      const float bv = bias[col];
#pragma unroll
      for (int r = 0; r < 4; ++r)
        tb[(kg * 4 + r) * 68 + fn * 16 + lr] = acc[fm][fn][r] + bv;
    }
#pragma unroll
    for (int it = 0; it < (BN / 16) / 8; ++it) {
      const int slot = it * 64 + lane;
      const int row16 = slot / (BN / 16);
      const int cg = slot % (BN / 16);
      const f32x4 a = *(const f32x4*)&tb[row16 * 68 + cg * 8];
      const f32x4 b2 = *(const f32x4*)&tb[row16 * 68 + cg * 8 + 4];
      const int grow = row0w + fm * 16 + row16;
      const size_t o = (size_t)grow * N + col0w + cg * 8;
      *(f32x4*)(Cf + o) = a;
      *(f32x4*)(Cf + o + 4) = b2;
    }
  }
}

// FF1 (GELU, BN=256, coalesced, XCD-swizzled) + folded weight-prep (blockIdx.y >= 32)
__global__ __launch_bounds__(256, 2) void ff1_fused(
    const ushort_t* __restrict__ Xh, const ushort_t* __restrict__ Xl,
    const ushort_t* __restrict__ W1th, const float* __restrict__ bias,
    ushort_t* __restrict__ Ch, ushort_t* __restrict__ Cl,
    const float* __restrict__ WqN, const float* __restrict__ WkN,
    const float* __restrict__ WvN, const float* __restrict__ WoN,
    const float* __restrict__ W1N, const float* __restrict__ W2N,
    ushort_t* __restrict__ WT4hN, ushort_t* __restrict__ W1thN, ushort_t* __restrict__ W2thN) {
  __shared__ __attribute__((aligned(16))) char pool[2 * (2 * 128 * 32 + 256 * 32) * 2];  // 64 KB
  if (blockIdx.y >= 32) {
    if (WqN == nullptr) return;
    const int wid = (blockIdx.y - 32) * 12 + blockIdx.x;
    wprep_dispatch((float(*)[65])pool, wid, WqN, WkN, WvN, WoN, W1N, W2N, WT4hN, W1thN, W2thN);
    return;
  }
  // swizzle within the 384 GEMM blocks (slots 0..383 of the dispatch)
  const int bid = blockIdx.x + blockIdx.y * 12;
  const int widb = (bid & 7) * 48 + (bid >> 3);
  const int bx = widb % 12, by = widb / 12;
  const int row0 = by * 128, col0 = bx * 256;
  f32x4 acc[4][8];
  mgemm_acc<128, 256, 32>(Xh, Xl, W1th, H_, acc, pool, row0, col0);
  const int tid = threadIdx.x;
  const int w = tid >> 6, lane = tid & 63;
  const int wm = w >> 1, wn = w & 1;
  const int kg = lane >> 4, lr = lane & 15;
  unsigned* tb = (unsigned*)pool + w * (16 * 132);
  const int row0w = row0 + wm * 64;
  const int col0w = col0 + wn * 128;
#pragma unroll
  for (int fm = 0; fm < 4; ++fm) {
#pragma unroll
    for (int fn = 0; fn < 8; ++fn) {
      const int col = col0w + fn * 16 + lr;
      const float bv = bias[col];
#pragma unroll
      for (int r = 0; r < 4; ++r) {
        float v = acc[fm][fn][r] + bv;
        float gl = 0.5f * v * (1.f + erff(v * 0.70710678118654752f));
        ushort_t h = f2bf(gl);
        ushort_t lo = f2bf(gl - bf2f(h));
        tb[(kg * 4 + r) * 132 + fn * 16 + lr] = ((unsigned)h << 16) | lo;
      }
    }
#pragma unroll
    for (int it = 0; it < 4; ++it) {
      const int slot = it * 64 + lane;
      const int row16 = slot >> 4, cg = slot & 15;
      unsigned r8[8];
      *(u32x4*)&r8[0] = *(const u32x4*)&tb[row16 * 132 + cg * 8];
      *(u32x4*)&r8[4] = *(const u32x4*)&tb[row16 * 132 + cg * 8 + 4];
      us8 h8, l8;
#pragma unroll
      for (int j = 0; j < 8; ++j) {
        h8[j] = (ushort_t)(r8[j] >> 16);
        l8[j] = (ushort_t)(r8[j] & 0xffffu);
      }
      const int grow = row0w + fm * 16 + row16;
      const size_t o = (size_t)grow * FF_ + col0w + cg * 8;
      *(us8*)(Ch + o) = h8;
      *(us8*)(Cl + o) = l8;
    }
  }
}

// ---------------- fused QKV (XCD-swizzled): coalesced Q/K epilogue; V transposed ----------------
__global__ __launch_bounds__(256) void qkv_m(const ushort_t* __restrict__ Xh, const ushort_t* __restrict__ Xl,
                      const ushort_t* __restrict__ WT4h,
                      const float* __restrict__ bq, const float* __restrict__ bk,
                      const float* __restrict__ bvv,
                      ushort_t* __restrict__ Qh, ushort_t* __restrict__ Ql,
                      ushort_t* __restrict__ Kh, ushort_t* __restrict__ Vth) {
  constexpr int ABYTES = 128 * 32 * 2;
  constexpr int BUF = 2 * ABYTES + 3 * ABYTES;      // 40 KB
  __shared__ __attribute__((aligned(16))) char pool[2 * BUF];   // 80 KB
  const int tid = threadIdx.x;
  const int w = tid >> 6, lane = tid & 63;
  const int wm = w >> 1, wn = w & 1;
  const int kgL = lane >> 4, lr = lane & 15;
  // XCD swizzle over 192 blocks (grid 6x32)
  const int bid = blockIdx.x + blockIdx.y * 6;
  const int widb = (bid & 7) * 24 + (bid >> 3);
  const int bxs = widb % 6, bys = widb / 6;
  const int row0 = bys * 128, col0 = bxs * 128;

  f32x4 acc[3][4][4];
#pragma unroll
  for (int z = 0; z < 3; ++z)
#pragma unroll
    for (int i = 0; i < 4; ++i)
#pragma unroll
      for (int j = 0; j < 4; ++j) acc[z][i][j] = (f32x4){0.f, 0.f, 0.f, 0.f};

  const int khL = kgL >> 1;
  const int swz = (((kgL & 1) ^ ((lr >> 2) & 1)) << 4);
  const int aB0 = khL * (128 * 32) + (wm * 64 + lr) * 32 + swz;
  const int bB0 = khL * (128 * 32) + (wn * 64 + lr) * 32 + swz;

  const ushort_t* gA_h = Xh + (size_t)row0 * H_;
  const ushort_t* gA_l = Xl + (size_t)row0 * H_;
  const ushort_t* gB0 = WT4h + (size_t)col0 * H_;
  const ushort_t* gB1 = WT4h + (size_t)H_ * H_ + (size_t)col0 * H_;
  const ushort_t* gB2 = WT4h + (size_t)2 * H_ * H_ + (size_t)col0 * H_;

  auto stageall = [&](int k0, char* buf) {
    stage_slice<128>(gA_h + k0, H_, buf);
    stage_slice<128>(gA_l + k0, H_, buf + ABYTES);
    stage_slice<128>(gB0 + k0, H_, buf + 2 * ABYTES);
    stage_slice<128>(gB1 + k0, H_, buf + 3 * ABYTES);
    stage_slice<128>(gB2 + k0, H_, buf + 4 * ABYTES);
  };

  const int nk = H_ / 32;   // 24
  stageall(0, pool);
  for (int k = 0; k < nk; ++k) {
    char* cur = pool + (k & 1) * BUF;
    if (k + 1 < nk) {
      stageall((k + 1) * 32, pool + ((k + 1) & 1) * BUF);
      asm volatile("s_waitcnt vmcnt(10)" ::: "memory");
    } else {
      asm volatile("s_waitcnt vmcnt(0)" ::: "memory");
    }
    __builtin_amdgcn_s_barrier();
    asm volatile("" ::: "memory");

    bf16x8 a_h[4], a_l[4];
#pragma unroll
    for (int fm = 0; fm < 4; ++fm) {
      a_h[fm] = *(const bf16x8*)(cur + aB0 + fm * 512);
      a_l[fm] = *(const bf16x8*)(cur + ABYTES + aB0 + fm * 512);
    }
#pragma unroll
    for (int z = 0; z < 3; ++z) {
      const char* bP = cur + (2 + z) * ABYTES;
      bf16x8 b_h[4];
#pragma unroll
      for (int fn = 0; fn < 4; ++fn) b_h[fn] = *(const bf16x8*)(bP + bB0 + fn * 512);
#pragma unroll
      for (int fm = 0; fm < 4; ++fm)
#pragma unroll
        for (int fn = 0; fn < 4; ++fn) {
          f32x4 c = acc[z][fm][fn];
          c = __builtin_amdgcn_mfma_f32_16x16x32_bf16(a_h[fm], b_h[fn], c, 0, 0, 0);
          c = __builtin_amdgcn_mfma_f32_16x16x32_bf16(a_l[fm], b_h[fn], c, 0, 0, 0);
          acc[z][fm][fn] = c;
        }
    }
    asm volatile("" ::: "memory");
    __builtin_amdgcn_s_barrier();
  }

  const int kg = kgL;
  unsigned* tb = (unsigned*)pool + w * (16 * 68);
  const int row0w = row0 + wm * 64;
  const int col0w = col0 + wn * 64;
#pragma unroll
  for (int z = 0; z < 2; ++z) {
    const float* bz = z == 0 ? bq : bk;
#pragma unroll
    for (int fm = 0; fm < 4; ++fm) {
#pragma unroll
      for (int fn = 0; fn < 4; ++fn) {
        const int col = col0w + fn * 16 + lr;
        const float bv = bz[col];
#pragma unroll
        for (int r = 0; r < 4; ++r) {
          float v = acc[z][fm][fn][r] + bv;
          ushort_t h = f2bf(v);
          ushort_t lo = f2bf(v - bf2f(h));
          tb[(kg * 4 + r) * 68 + fn * 16 + lr] = ((unsigned)h << 16) | lo;
        }
      }
#pragma unroll
      for (int it = 0; it < 2; ++it) {
        const int slot = it * 64 + lane;
        const int row16 = slot >> 3, cg = slot & 7;
        unsigned r8[8];
        *(u32x4*)&r8[0] = *(const u32x4*)&tb[row16 * 68 + cg * 8];
        *(u32x4*)&r8[4] = *(const u32x4*)&tb[row16 * 68 + cg * 8 + 4];
        us8 h8, l8;
#pragma unroll
        for (int j = 0; j < 8; ++j) {
          h8[j] = (ushort_t)(r8[j] >> 16);
          l8[j] = (ushort_t)(r8[j] & 0xffffu);
        }
        const int grow = row0w + fm * 16 + row16;
        const size_t o = (size_t)grow * H_ + col0w + cg * 8;
        if (z == 0) {
          *(us8*)(Qh + o) = h8;
          *(us8*)(Ql + o) = l8;
        } else {
          *(us8*)(Kh + o) = h8;
        }
      }
    }
  }
#pragma unroll
  for (int fn = 0; fn < 4; ++fn) {
    const int col = col0w + fn * 16 + lr;
    const float bv = bvv[col];
#pragma unroll
    for (int fm = 0; fm < 4; ++fm) {
      const int rowb = row0w + fm * 16 + kg * 4;
      us4 h4;
#pragma unroll
      for (int r = 0; r < 4; ++r) h4[r] = f2bf(acc[2][fm][fn][r] + bv);
      const int bb2 = rowb >> 8, s0 = rowb & 255;
      const int hh2 = col >> 6, d = col & 63;
      *(us4*)(Vth + ((size_t)(bb2 * NH_ + hh2) * DH_ + d) * S_ + s0) = h4;
    }
  }
}

// ---------------- MFMA flash attention, double-buffered K/V ----------------
__global__ __launch_bounds__(256, 3) void attn_mfma(
    const ushort_t* __restrict__ Qh, const ushort_t* __restrict__ Ql,
    const ushort_t* __restrict__ Kh, const ushort_t* __restrict__ Vth,
    const int* __restrict__ amask,
    ushort_t* __restrict__ Oh, ushort_t* __restrict__ Ol) {
  const int bid = blockIdx.x;
  const int qt = bid / 192;
  const int gh = bid - qt * 192;
  const int b = gh / NH_;
  const int h = gh - b * NH_;
  __shared__ __attribute__((aligned(16))) ushort_t sKh[2][64 * 64];
  __shared__ __attribute__((aligned(16))) ushort_t sVh[2][64 * 64];
  __shared__ __attribute__((aligned(16))) unsigned sP[4][16 * 68];
  __shared__ float sBias[2][64];
  const int tid = threadIdx.x;
  const int w = tid >> 6, lane = tid & 63;
  const int kg = lane >> 4, lr = lane & 15;

  const int qrow = b * S_ + qt * 64 + w * 16 + lr;
  bf16x8 qfh[2], qfl[2];
#pragma unroll
  for (int ds2 = 0; ds2 < 2; ++ds2) {
    const size_t off = (size_t)qrow * H_ + h * DH_ + ds2 * 32 + kg * 8;
    qfh[ds2] = *(const bf16x8*)(Qh + off);
    qfl[ds2] = *(const bf16x8*)(Ql + off);
  }

  f32x4 ctx[4];
#pragma unroll
  for (int i = 0; i < 4; ++i) ctx[i] = (f32x4){0.f, 0.f, 0.f, 0.f};
  float mrow[4], lrw[4];
#pragma unroll
  for (int r = 0; r < 4; ++r) { mrow[r] = -1e30f; lrw[r] = 0.f; }

  unsigned* sPw = &sP[w][0];

  auto stageKV = [&](int kt, int bufi) {
#pragma unroll
    for (int i = 0; i < 2; ++i) {
      const int v = tid + i * 256;
      const int row = v >> 3;
      const int c16 = (v & 7) ^ (row & 7);
      const size_t kgl = (size_t)(b * S_ + kt * 64 + row) * H_ + h * DH_ + c16 * 8;
      gload16(Kh + kgl, (char*)&sKh[bufi][0] + v * 16);
      const size_t vgl = (size_t)((b * NH_ + h) * DH_ + row) * S_ + kt * 64 + c16 * 8;
      gload16(Vth + vgl, (char*)&sVh[bufi][0] + v * 16);
    }
    if (tid < 64) sBias[bufi][tid] = (amask[b * S_ + kt * 64 + tid] > 0) ? 0.f : -1e9f;
  };

  stageKV(0, 0);
  for (int kt = 0; kt < 4; ++kt) {
    const int bi = kt & 1;
    if (kt < 3) {
      stageKV(kt + 1, bi ^ 1);
      asm volatile("s_waitcnt vmcnt(4) lgkmcnt(0)" ::: "memory");
    } else {
      asm volatile("s_waitcnt vmcnt(0) lgkmcnt(0)" ::: "memory");
    }
    __builtin_amdgcn_s_barrier();
    asm volatile("" ::: "memory");

    // QK^T
    f32x4 sc[4];
#pragma unroll
    for (int kf = 0; kf < 4; ++kf) sc[kf] = (f32x4){0.f, 0.f, 0.f, 0.f};
#pragma unroll
    for (int kf = 0; kf < 4; ++kf) {
      const int krow = kf * 16 + lr;
#pragma unroll
      for (int ds2 = 0; ds2 < 2; ++ds2) {
        const int cb = (ds2 * 64 + kg * 16) ^ ((krow & 7) << 4);
        const bf16x8 kvh = *(const bf16x8*)((const char*)&sKh[bi][0] + krow * 128 + cb);
        sc[kf] = __builtin_amdgcn_mfma_f32_16x16x32_bf16(qfh[ds2], kvh, sc[kf], 0, 0, 0);
        sc[kf] = __builtin_amdgcn_mfma_f32_16x16x32_bf16(qfl[ds2], kvh, sc[kf], 0, 0, 0);
      }
    }
    float bsv[4];
#pragma unroll
    for (int kf = 0; kf < 4; ++kf) bsv[kf] = sBias[bi][kf * 16 + lr];

#pragma unroll
    for (int r = 0; r < 4; ++r) {
      float sv[4];
      float tmax = -1e30f;
#pragma unroll
      for (int kf = 0; kf < 4; ++kf) {
        sv[kf] = sc[kf][r] * 0.125f + bsv[kf];
        tmax = fmaxf(tmax, sv[kf]);
      }
#pragma unroll
      for (int o = 8; o > 0; o >>= 1) tmax = fmaxf(tmax, __shfl_xor(tmax, o, 64));
      const float mnew = fmaxf(mrow[r], tmax);
      const float corr = expf(mrow[r] - mnew);
      float ls = 0.f;
      const int qoff = (kg * 4 + r) * 68;
#pragma unroll
      for (int kf = 0; kf < 4; ++kf) {
        const float pe = expf(sv[kf] - mnew);
        ls += pe;
        const ushort_t hi = f2bf(pe);
        const ushort_t lo = f2bf(pe - bf2f(hi));
        sPw[qoff + kf * 16 + lr] = ((unsigned)hi << 16) | lo;
      }
#pragma unroll
      for (int o = 8; o > 0; o >>= 1) ls += __shfl_xor(ls, o, 64);
      lrw[r] = lrw[r] * corr + ls;
      mrow[r] = mnew;
#pragma unroll
      for (int df = 0; df < 4; ++df) ctx[df][r] *= corr;
    }

    // PV
#pragma unroll
    for (int ks = 0; ks < 2; ++ks) {
      unsigned w8[8];
      *(u32x4*)&w8[0] = *(const u32x4*)(sPw + lr * 68 + ks * 32 + kg * 8);
      *(u32x4*)&w8[4] = *(const u32x4*)(sPw + lr * 68 + ks * 32 + kg * 8 + 4);
      union { bf16x8 v; ushort_t u[8]; } ph, pl;
#pragma unroll
      for (int j = 0; j < 8; ++j) { ph.u[j] = (ushort_t)(w8[j] >> 16); pl.u[j] = (ushort_t)(w8[j] & 0xffffu); }
#pragma unroll
      for (int df = 0; df < 4; ++df) {
        const int vrow = df * 16 + lr;
        const int cb = (ks * 64 + kg * 16) ^ ((vrow & 7) << 4);
        const bf16x8 vvh = *(const bf16x8*)((const char*)&sVh[bi][0] + vrow * 128 + cb);
        ctx[df] = __builtin_amdgcn_mfma_f32_16x16x32_bf16(ph.v, vvh, ctx[df], 0, 0, 0);
        ctx[df] = __builtin_amdgcn_mfma_f32_16x16x32_bf16(pl.v, vvh, ctx[df], 0, 0, 0);
      }
    }
    asm volatile("" ::: "memory");
    __builtin_amdgcn_s_barrier();
  }

#pragma unroll
  for (int r = 0; r < 4; ++r) {
    const float inv = 1.f / lrw[r];
    const int tok = b * S_ + qt * 64 + w * 16 + kg * 4 + r;
#pragma unroll
    for (int df = 0; df < 4; ++df) {
      const float v = ctx[df][r] * inv;
      const ushort_t hi = f2bf(v);
      const size_t o = (size_t)tok * H_ + h * DH_ + df * 16 + lr;
      Oh[o] = hi;
      Ol[o] = f2bf(v - bf2f(hi));
    }
  }
}

// ---------------- CRF v6: readlane broadcast + LDS prefetch one step ahead ----------------
__global__ __launch_bounds__(128) void crf_kernel(const float* __restrict__ emis, const int* __restrict__ tags,
                          const int* __restrict__ amask,
                          const float* __restrict__ crf_start, const float* __restrict__ crf_end,
                          const float* __restrict__ trans,
                          float* __restrict__ partial, float* __restrict__ out) {
  const int b = blockIdx.x;
  const int tid = threadIdx.x;
  const int wv = tid >> 6;
  const int lane = tid & 63;
  __shared__ float sE[S_ * T_];
  __shared__ float sM[S_];
  __shared__ float trs[T_ * T_];
  __shared__ unsigned char hist[S_ - 1][16];
  __shared__ float pathf[S_];
  for (int i = tid; i < S_ * T_; i += 128) {
    const int s = i / T_, t = i - s * T_;
    sE[i] = emis[((size_t)s * B_ + b) * T_ + t];
  }
  for (int i = tid; i < S_; i += 128) sM[i] = (float)amask[b * S_ + i];
  for (int i = tid; i < T_ * T_; i += 128) trs[i] = trans[i];
  __syncthreads();

  const int t = lane;
  const bool act = t < T_;
  float trc[T_];
#pragma unroll
  for (int p = 0; p < T_; ++p) trc[p] = act ? trs[p * T_ + t] : 0.f;

  if (wv == 0) {
    float alpha = act ? crf_start[t] + sE[t] : 0.f;
    float eN = act ? sE[T_ + t] : 0.f;
    float mN = sM[1];
    for (int s = 1; s < S_; ++s) {
      const float e = eN, mm = mN;
      if (s + 1 < S_) {                       // prefetch next step's LDS reads
        eN = act ? sE[(s + 1) * T_ + t] : 0.f;
        mN = sM[s + 1];
      }
      float ap[T_];
#pragma unroll
      for (int p = 0; p < T_; ++p) ap[p] = rdlane(alpha, p);
      if (act) {
        float v[T_];
#pragma unroll
        for (int p = 0; p < T_; ++p) v[p] = ap[p] + trc[p];
        float m0 = fmaxf(fmaxf(v[0], v[1]), fmaxf(v[2], v[3]));
        float m1 = fmaxf(fmaxf(v[4], v[5]), fmaxf(v[6], v[7]));
        const float mx = fmaxf(fmaxf(m0, m1), v[8]);
        float sum = 0.f;
#pragma unroll
        for (int p = 0; p < T_; ++p) sum += __expf(v[p] - mx);
        const float na = mx + __logf(sum) + e;
        if (mm > 0.f) alpha = na;
      }
    }
    float nsum = 0.f;
    int len = 0;
#pragma unroll
    for (int j = 0; j < 4; ++j) {
      const int s = lane + j * 64;
      const int mk = (sM[s] > 0.f) ? 1 : 0;
      len += mk;
      if (s >= 1 && mk) {
        const int tc = tags[b * S_ + s], tp = tags[b * S_ + s - 1];
        nsum += trs[tp * T_ + tc] + sE[s * T_ + tc];
      }
    }
#pragma unroll
    for (int o = 32; o > 0; o >>= 1) {
      nsum += __shfl_xor(nsum, o, 64);
      len += __shfl_xor(len, o, 64);
    }
    const float fz = act ? alpha + crf_end[t] : -1e30f;
    float zp[T_];
#pragma unroll
    for (int p = 0; p < T_; ++p) zp[p] = rdlane(fz, p);
    if (lane == 0) {
      float mx = -1e30f;
#pragma unroll
      for (int p = 0; p < T_; ++p) mx = fmaxf(mx, zp[p]);
      float sum = 0.f;
#pragma unroll
      for (int p = 0; p < T_; ++p) sum += __expf(zp[p] - mx);
      const float logZ = mx + __logf(sum);
      const int tg0 = tags[b * S_];
      const float score = nsum + crf_start[tg0] + sE[tg0] + crf_end[tags[b * S_ + len - 1]];
      partial[b] = score - logZ;
    }
  } else {
    float vit = act ? crf_start[t] + sE[t] : 0.f;
    float eN = act ? sE[T_ + t] : 0.f;
    float mN = sM[1];
    for (int s = 1; s < S_; ++s) {
      const float e = eN, mm = mN;
      if (s + 1 < S_) {
        eN = act ? sE[(s + 1) * T_ + t] : 0.f;
        mN = sM[s + 1];
      }
      float vp[T_];
#pragma unroll
      for (int p = 0; p < T_; ++p) vp[p] = rdlane(vit, p);
      if (act) {
        float best = -1e30f; int bi = 0;
#pragma unroll
        for (int p = 0; p < T_; ++p) {
          const float scv = vp[p] + trc[p];
          if (scv > best) { best = scv; bi = p; }
        }
        if (mm > 0.f) {
          vit = best + e;
          hist[s - 1][t] = (unsigned char)bi;
        } else {
          hist[s - 1][t] = (unsigned char)t;
        }
      }
    }
    const float fv = act ? vit + crf_end[t] : -1e30f;
    float wp[T_];
#pragma unroll
    for (int p = 0; p < T_; ++p) wp[p] = rdlane(fv, p);
    if (lane == 0) {
      float best = -1e30f; int lastTag = 0;
#pragma unroll
      for (int p = 0; p < T_; ++p) {
        if (wp[p] > best) { best = wp[p]; lastTag = p; }
      }
      int tc = lastTag;
      pathf[S_ - 1] = (float)tc;
      for (int i = S_ - 2; i >= 0; --i) {
        tc = hist[i][tc];
        pathf[i] = (float)tc;
      }
    }
  }
  __syncthreads();
#pragma unroll
  for (int j = 0; j < 2; ++j) {
    const int s = tid + j * 128;
    out[1 + b * S_ + s] = pathf[s];
  }
}

__global__ __launch_bounds__(64) void crf_final(const float* __restrict__ partial, float* __restrict__ out) {
  const int lane = threadIdx.x;
  float v = (lane < B_) ? partial[lane] : 0.f;
#pragma unroll
  for (int o = 32; o > 0; o >>= 1) v += __shfl_xor(v, o, 64);
  if (lane == 0) out[0] = -(v * (1.f / B_));
}

extern "C" void kernel_launch(void* const* d_in, const int* in_sizes, int n_in,
                              void* d_out, int out_size, void* d_ws, size_t ws_size,
                              hipStream_t stream) {
  const int* input_ids = (const int*)d_in[0];
  const int* token_type_ids = (const int*)d_in[1];
  const int* attention_mask = (const int*)d_in[2];
  const int* tags = (const int*)d_in[3];
  const float* word_emb = (const float*)d_in[4];
  const float* pos_emb = (const float*)d_in[5];
  const float* type_emb = (const float*)d_in[6];
  const float* emb_ln_g = (const float*)d_in[7];
  const float* emb_ln_b = (const float*)d_in[8];
  const float* Wq = (const float*)d_in[9];
  const float* bq = (const float*)d_in[10];
  const float* Wk = (const float*)d_in[11];
  const float* bk = (const float*)d_in[12];
  const float* Wv = (const float*)d_in[13];
  const float* bv = (const float*)d_in[14];
  const float* Wo = (const float*)d_in[15];
  const float* bo = (const float*)d_in[16];
  const float* ln1_g = (const float*)d_in[17];
  const float* ln1_b = (const float*)d_in[18];
  const float* W1 = (const float*)d_in[19];
  const float* b1 = (const float*)d_in[20];
  const float* W2 = (const float*)d_in[21];
  const float* b2 = (const float*)d_in[22];
  const float* ln2_g = (const float*)d_in[23];
  const float* ln2_b = (const float*)d_in[24];
  const float* dense_W = (const float*)d_in[25];
  const float* dense_b = (const float*)d_in[26];
  const float* crf_start = (const float*)d_in[27];
  const float* crf_end = (const float*)d_in[28];
  const float* crf_trans = (const float*)d_in[29];

  constexpr size_t NTOK = (size_t)B_ * S_;        // 4096
  constexpr size_t XSZ = NTOK * H_;               // 3,145,728
  constexpr size_t WT4SZ = (size_t)4 * H_ * H_;   // 2,359,296
  constexpr size_t WFSZ = (size_t)H_ * FF_;       // 2,359,296

  char* p = (char*)d_ws;
  float* TMP = (float*)p;          p += XSZ * 4;
  char* UN = p;                    p += 8 * XSZ * 2;     // 50.33 MB union
  ushort_t* Qh = (ushort_t*)UN;
  ushort_t* Ql = Qh + XSZ;
  ushort_t* Kh = Ql + XSZ;
  ushort_t* Vth = Kh + XSZ;
  ushort_t* CTXh = Vth + XSZ;
  ushort_t* CTXl = CTXh + XSZ;
  ushort_t* FFh = (ushort_t*)UN;                        // aliases QKV after dead
  ushort_t* FFl = FFh + NTOK * FF_;
  ushort_t* Xh = (ushort_t*)p;     p += XSZ * 2;
  ushort_t* Xl = (ushort_t*)p;     p += XSZ * 2;
  ushort_t* WT4h2 = (ushort_t*)p;  p += WT4SZ * 2 * 2;  // double-buffered
  ushort_t* W1th2 = (ushort_t*)p;  p += WFSZ * 2 * 2;
  ushort_t* W2th2 = (ushort_t*)p;  p += WFSZ * 2 * 2;
  float* EM = (float*)p;           p += (size_t)S_ * B_ * T_ * 4;
  float* PART = (float*)p;         p += B_ * 4;

  emb_ln_kernel<<<dim3(4096), dim3(256), 0, stream>>>(input_ids, token_type_ids, word_emb, pos_emb,
                                                      type_emb, emb_ln_g, emb_ln_b, Xh, Xl);
  // layer 0 weights into parity 0
  wprep_k<<<dim3(1728), dim3(256), 0, stream>>>(Wq, Wk, Wv, Wo, W1, W2, WT4h2, W1th2, W2th2);

  for (int l = 0; l < L_; ++l) {
    const int pr = l & 1, pn = (l + 1) & 1;
    ushort_t* WT4h = WT4h2 + (size_t)pr * WT4SZ;
    ushort_t* W1th = W1th2 + (size_t)pr * WFSZ;
    ushort_t* W2th = W2th2 + (size_t)pr * WFSZ;
    const bool hasNext = (l + 1 < L_);
    const size_t wo_n = (size_t)(l + 1) * H_ * H_;

    qkv_m<<<dim3(6, 32), dim3(256), 0, stream>>>(Xh, Xl, WT4h, bq + (size_t)l * H_,
                                                 bk + (size_t)l * H_, bv + (size_t)l * H_,
                                                 Qh, Ql, Kh, Vth);
    attn_mfma<<<dim3(768), dim3(256), 0, stream>>>(Qh, Ql, Kh, Vth, attention_mask, CTXh, CTXl);
    mgemm<128, 128, 32, 0><<<dim3(6, 32), dim3(256), 0, stream>>>(
        CTXh, CTXl, WT4h + (size_t)3 * H_ * H_,
        bo + (size_t)l * H_, TMP, nullptr, nullptr, H_, H_);
    ln_kernel<<<dim3(4096), dim3(256), 0, stream>>>(Xh, Xl, TMP, ln1_g + (size_t)l * H_,
                                                    ln1_b + (size_t)l * H_, Xh, Xl);
    ff1_fused<<<dim3(12, 32 + 144), dim3(256), 0, stream>>>(
        Xh, Xl, W1th, b1 + (size_t)l * FF_, FFh, FFl,
        hasNext ? Wq + wo_n : nullptr, Wk + wo_n, Wv + wo_n, Wo + wo_n,
        W1 + (size_t)(l + 1) * WFSZ, W2 + (size_t)(l + 1) * WFSZ,
        WT4h2 + (size_t)pn * WT4SZ, W1th2 + (size_t)pn * WFSZ, W2th2 + (size_t)pn * WFSZ);
    mgemm<128, 128, 32, 0><<<dim3(6, 32), dim3(256), 0, stream>>>(
        FFh, FFl, W2th, b2 + (size_t)l * H_, TMP, nullptr, nullptr, H_, FF_);
    if (l + 1 < L_) {
      ln_kernel<<<dim3(4096), dim3(256), 0, stream>>>(Xh, Xl, TMP, ln2_g + (size_t)l * H_,
                                                      ln2_b + (size_t)l * H_, Xh, Xl);
    } else {
      ln_emis_kernel<<<dim3(4096), dim3(256), 0, stream>>>(Xh, Xl, TMP, ln2_g + (size_t)l * H_,
                                                           ln2_b + (size_t)l * H_, dense_W,
                                                           dense_b, EM);
    }
  }

  crf_kernel<<<dim3(B_), dim3(128), 0, stream>>>(EM, tags, attention_mask, crf_start, crf_end,
                                                 crf_trans, PART, (float*)d_out);
  crf_final<<<dim3(1), dim3(64), 0, stream>>>(PART, (float*)d_out);
}